// Round 1
// baseline (373.331 us; speedup 1.0000x reference)
//
#include <hip/hip_runtime.h>
#include <hip/hip_bf16.h>

typedef unsigned short u16;
typedef __bf16 bf16x8 __attribute__((ext_vector_type(8)));
typedef u16 u16x8 __attribute__((ext_vector_type(8)));
typedef float f32x4 __attribute__((ext_vector_type(4)));

#define T_SEQ 2048
#define DMODEL 2048
#define NHEAD 16
#define HDIM 128
#define ATT_SCALE 0.08838834764831843f

__device__ __forceinline__ u16 f2bf(float f) {
    return __builtin_bit_cast(u16, __float2bfloat16(f));
}
__device__ __forceinline__ bf16x8 as_bf(u16x8 v) {
    return __builtin_bit_cast(bf16x8, v);
}

// ---------------- cast fp32 -> bf16 (8 elems / thread) ----------------
__global__ __launch_bounds__(256) void cast_f32_bf16(const float* __restrict__ src,
                                                     u16* __restrict__ dst, int n8) {
    int i = blockIdx.x * 256 + threadIdx.x;
    if (i >= n8) return;
    float4 a = ((const float4*)src)[2 * i];
    float4 b = ((const float4*)src)[2 * i + 1];
    u16x8 o;
    o[0] = f2bf(a.x); o[1] = f2bf(a.y); o[2] = f2bf(a.z); o[3] = f2bf(a.w);
    o[4] = f2bf(b.x); o[5] = f2bf(b.y); o[6] = f2bf(b.z); o[7] = f2bf(b.w);
    *(u16x8*)(dst + (size_t)i * 8) = o;
}

// ---------------- row RMSNorm over D=2048, write bf16 ----------------
__global__ __launch_bounds__(256) void rmsnorm_row(const float* __restrict__ x,
                                                   u16* __restrict__ xn) {
    const int row = blockIdx.x, tid = threadIdx.x;
    const float* xr = x + (size_t)row * DMODEL;
    float4 a = ((const float4*)xr)[2 * tid];
    float4 b = ((const float4*)xr)[2 * tid + 1];
    float ss = a.x*a.x + a.y*a.y + a.z*a.z + a.w*a.w
             + b.x*b.x + b.y*b.y + b.z*b.z + b.w*b.w;
#pragma unroll
    for (int off = 32; off; off >>= 1) ss += __shfl_xor(ss, off);
    __shared__ float red[4];
    if ((tid & 63) == 0) red[tid >> 6] = ss;
    __syncthreads();
    float tot = red[0] + red[1] + red[2] + red[3];
    float r = rsqrtf(tot * (1.f / DMODEL) + 1e-6f);
    u16x8 o;
    o[0] = f2bf(a.x*r); o[1] = f2bf(a.y*r); o[2] = f2bf(a.z*r); o[3] = f2bf(a.w*r);
    o[4] = f2bf(b.x*r); o[5] = f2bf(b.y*r); o[6] = f2bf(b.z*r); o[7] = f2bf(b.w*r);
    *(u16x8*)(xn + (size_t)row * DMODEL + tid * 8) = o;
}

// ---------------- GEMM: C[m][n] = sum_k A[m][k]*B[n][k] (+resid) ----------------
// A: MxK bf16 row-major, B: NxK bf16 row-major (i.e. B^T GEMM). C fp32.
// 128x128 tile, BK=32, 256 threads = 4 waves, each wave 64x64 (4x4 MFMA frags).
__global__ __launch_bounds__(256) void gemm_bt(const u16* __restrict__ A,
                                               const u16* __restrict__ B,
                                               float* __restrict__ C,
                                               const float* __restrict__ resid,
                                               int M, int N, int K) {
    __shared__ u16 As[128 * 32];
    __shared__ u16 Bs[128 * 32];
    const int bm = blockIdx.y * 128, bn = blockIdx.x * 128;
    const int tid = threadIdx.x, lane = tid & 63, wid = tid >> 6;
    const int wr = (wid >> 1) * 64, wc = (wid & 1) * 64;
    const int fr = lane & 15, fc = (lane >> 4) * 8;

    f32x4 acc[4][4] = {};

    // staging assignment: 512 chunks of 8 elems; thread handles idx = tid, tid+256
    const int r0 = tid >> 2, c0 = (tid & 3) << 3;
    const int r1 = (tid + 256) >> 2, c1 = c0;

    for (int k0 = 0; k0 < K; k0 += 32) {
        u16x8 a0 = *(const u16x8*)(A + (size_t)(bm + r0) * K + k0 + c0);
        u16x8 a1 = *(const u16x8*)(A + (size_t)(bm + r1) * K + k0 + c1);
        u16x8 b0 = *(const u16x8*)(B + (size_t)(bn + r0) * K + k0 + c0);
        u16x8 b1 = *(const u16x8*)(B + (size_t)(bn + r1) * K + k0 + c1);
        *(u16x8*)&As[r0 * 32 + c0] = a0;
        *(u16x8*)&As[r1 * 32 + c1] = a1;
        *(u16x8*)&Bs[r0 * 32 + c0] = b0;
        *(u16x8*)&Bs[r1 * 32 + c1] = b1;
        __syncthreads();

        u16x8 af[4], bfm[4];
#pragma unroll
        for (int m = 0; m < 4; ++m)
            af[m] = *(const u16x8*)&As[(wr + m * 16 + fr) * 32 + fc];
#pragma unroll
        for (int n = 0; n < 4; ++n)
            bfm[n] = *(const u16x8*)&Bs[(wc + n * 16 + fr) * 32 + fc];
#pragma unroll
        for (int m = 0; m < 4; ++m)
#pragma unroll
            for (int n = 0; n < 4; ++n)
                acc[m][n] = __builtin_amdgcn_mfma_f32_16x16x32_bf16(
                    as_bf(af[m]), as_bf(bfm[n]), acc[m][n], 0, 0, 0);
        __syncthreads();
    }

#pragma unroll
    for (int m = 0; m < 4; ++m)
#pragma unroll
        for (int n = 0; n < 4; ++n)
#pragma unroll
            for (int r = 0; r < 4; ++r) {
                int row = bm + wr + m * 16 + (lane >> 4) * 4 + r;
                int col = bn + wc + n * 16 + fr;
                float val = acc[m][n][r];
                if (resid) val += resid[(size_t)row * N + col];
                C[(size_t)row * N + col] = val;
            }
}

// ---------------- per-head RMSNorm + RoPE for q,k; scatter v ----------------
// qkv fp32: [T][6144] with channels (group,head,dim); writes:
//  q_bf/k_bf/v_bf: [h][T][128] bf16 ; k_out/v_out: [T][h][128] fp32
__global__ __launch_bounds__(256) void rope_split(const float* __restrict__ qkv,
                                                  const float* __restrict__ cosb,
                                                  const float* __restrict__ sinb,
                                                  u16* __restrict__ q_bf,
                                                  u16* __restrict__ k_bf,
                                                  u16* __restrict__ v_bf,
                                                  float* __restrict__ k_out,
                                                  float* __restrict__ v_out) {
    const int t = blockIdx.x, tid = threadIdx.x, wid = tid >> 6, lane = tid & 63;
    const float* row = qkv + (size_t)t * (3 * DMODEL);
    const float c = cosb[t * 64 + lane];
    const float s = sinb[t * 64 + lane];

    for (int task = wid; task < 32; task += 4) {
        float x1 = row[task * 128 + lane];
        float x2 = row[task * 128 + 64 + lane];
        float ss = x1 * x1 + x2 * x2;
#pragma unroll
        for (int off = 32; off; off >>= 1) ss += __shfl_xor(ss, off);
        float r = rsqrtf(ss * (1.f / 128.f) + 1e-6f);
        float n1 = x1 * r, n2 = x2 * r;
        float o1 = n1 * c - n2 * s;
        float o2 = n1 * s + n2 * c;
        if (task < 16) {
            size_t base = ((size_t)task * T_SEQ + t) * 128 + lane;
            q_bf[base] = f2bf(o1);
            q_bf[base + 64] = f2bf(o2);
        } else {
            int hh = task - 16;
            size_t base = ((size_t)hh * T_SEQ + t) * 128 + lane;
            k_bf[base] = f2bf(o1);
            k_bf[base + 64] = f2bf(o2);
            size_t ob = (size_t)t * DMODEL + hh * 128 + lane;
            k_out[ob] = o1;
            k_out[ob + 64] = o2;
        }
    }
    // v passthrough
    for (int i = tid; i < DMODEL; i += 256) {
        float val = row[2 * DMODEL + i];
        v_out[(size_t)t * DMODEL + i] = val;
        int hh = i >> 7, d = i & 127;
        v_bf[((size_t)hh * T_SEQ + t) * 128 + d] = f2bf(val);
    }
}

// ---------------- causal flash attention ----------------
// grid (T/64, h). 4 waves; wave w owns q rows [qt*64+16w, +16).
// Swapped QK^T: S^T frags (kv x q) so row-softmax = in-lane + shfl_xor{16,32}.
__global__ __launch_bounds__(256) void attn_fwd(const u16* __restrict__ qb,
                                                const u16* __restrict__ kb,
                                                const u16* __restrict__ vb,
                                                u16* __restrict__ xout) {
    __shared__ u16 Ks[32 * 136];     // [kv][128] pad->136 (2-way banks)
    __shared__ u16 Vt[128 * 40];     // [d][kv] pad->40
    __shared__ u16 Ps[4][16 * 32];   // per-wave P [q][kv]

    const int qt = blockIdx.x, head = blockIdx.y;
    const int tid = threadIdx.x, wid = tid >> 6, lane = tid & 63;
    const int fr = lane & 15, fg = lane >> 4;
    const u16* kh = kb + (size_t)head * T_SEQ * 128;
    const u16* vh = vb + (size_t)head * T_SEQ * 128;
    const u16* qh = qb + (size_t)head * T_SEQ * 128;
    const int q0 = qt * 64 + wid * 16;
    const int qrow_g = q0 + fr;

    u16x8 bq[4];
    {
        const u16* qrow = qh + (size_t)(q0 + fr) * 128 + fg * 8;
#pragma unroll
        for (int cc = 0; cc < 4; ++cc) bq[cc] = *(const u16x8*)(qrow + cc * 32);
    }

    f32x4 o[8] = {};
    float m_run = -1e30f, l_run = 0.f;
    const int nkv = (qt + 1) * 64;

    for (int kv0 = 0; kv0 < nkv; kv0 += 32) {
        // stage K and V^T
#pragma unroll
        for (int i = 0; i < 2; ++i) {
            int idx = tid + 256 * i;
            int r = idx >> 4, c = (idx & 15) << 3;
            u16x8 kd = *(const u16x8*)(kh + (size_t)(kv0 + r) * 128 + c);
            *(u16x8*)&Ks[r * 136 + c] = kd;
            u16x8 vd = *(const u16x8*)(vh + (size_t)(kv0 + r) * 128 + c);
#pragma unroll
            for (int j = 0; j < 8; ++j) Vt[(c + j) * 40 + r] = vd[j];
        }
        __syncthreads();

        // S^T = K . Q^T  (2 sub-tiles of 16 kv)
        float pv[2][4];
        float corr;
        {
            float tv[2][4];
            float mx = -1e30f;
#pragma unroll
            for (int sub = 0; sub < 2; ++sub) {
                f32x4 sacc = {0.f, 0.f, 0.f, 0.f};
#pragma unroll
                for (int c4 = 0; c4 < 4; ++c4) {
                    u16x8 ak = *(const u16x8*)&Ks[(sub * 16 + fr) * 136 + c4 * 32 + fg * 8];
                    sacc = __builtin_amdgcn_mfma_f32_16x16x32_bf16(
                        as_bf(ak), as_bf(bq[c4]), sacc, 0, 0, 0);
                }
#pragma unroll
                for (int r = 0; r < 4; ++r) {
                    int kvg = kv0 + sub * 16 + fg * 4 + r;
                    float sv = sacc[r] * ATT_SCALE;
                    sv = (kvg <= qrow_g) ? sv : -1e30f;
                    tv[sub][r] = sv;
                    mx = fmaxf(mx, sv);
                }
            }
            mx = fmaxf(mx, __shfl_xor(mx, 16));
            mx = fmaxf(mx, __shfl_xor(mx, 32));
            float m_new = fmaxf(m_run, mx);
            corr = __expf(m_run - m_new);
            float rs = 0.f;
#pragma unroll
            for (int sub = 0; sub < 2; ++sub)
#pragma unroll
                for (int r = 0; r < 4; ++r) {
                    float e = __expf(tv[sub][r] - m_new);
                    pv[sub][r] = e;
                    rs += e;
                }
            rs += __shfl_xor(rs, 16);
            rs += __shfl_xor(rs, 32);
            l_run = l_run * corr + rs;
            m_run = m_new;
        }

        // write P (bf16) to per-wave LDS [q][kv]
        {
            u16* pw = &Ps[wid][fr * 32 + fg * 4];
#pragma unroll
            for (int sub = 0; sub < 2; ++sub)
#pragma unroll
                for (int r = 0; r < 4; ++r) pw[sub * 16 + r] = f2bf(pv[sub][r]);
        }

        // rescale O: need corr of q-row (fg*4+r) -> held in lane (fg*4+r)
        float ct[4];
#pragma unroll
        for (int r = 0; r < 4; ++r) ct[r] = __shfl(corr, fg * 4 + r);
#pragma unroll
        for (int f = 0; f < 8; ++f)
#pragma unroll
            for (int r = 0; r < 4; ++r) o[f][r] *= ct[r];

        // PV: O[q][d] += P[q][kv] * V[kv][d]
        u16x8 pa = *(const u16x8*)&Ps[wid][fr * 32 + fg * 8];
#pragma unroll
        for (int f = 0; f < 8; ++f) {
            u16x8 vB = *(const u16x8*)&Vt[(f * 16 + fr) * 40 + fg * 8];
            o[f] = __builtin_amdgcn_mfma_f32_16x16x32_bf16(
                as_bf(pa), as_bf(vB), o[f], 0, 0, 0);
        }
        __syncthreads();
    }

    // epilogue: divide by l (per q-row) and store bf16
    float li[4];
#pragma unroll
    for (int r = 0; r < 4; ++r) li[r] = __shfl(l_run, fg * 4 + r);
#pragma unroll
    for (int f = 0; f < 8; ++f)
#pragma unroll
        for (int r = 0; r < 4; ++r) {
            int trow = q0 + fg * 4 + r;
            float val = o[f][r] / li[r];
            xout[(size_t)trow * DMODEL + head * 128 + f * 16 + fr] = f2bf(val);
        }
}

extern "C" void kernel_launch(void* const* d_in, const int* in_sizes, int n_in,
                              void* d_out, int out_size, void* d_ws, size_t ws_size,
                              hipStream_t stream) {
    const float* x_in = (const float*)d_in[0];
    const float* w_qkv = (const float*)d_in[1];
    const float* w_o = (const float*)d_in[2];
    const float* cosb = (const float*)d_in[3];
    const float* sinb = (const float*)d_in[4];

    float* out = (float*)d_out;
    float* k_out = out + 4194304;
    float* v_out = out + 8388608;

    char* ws = (char*)d_ws;
    u16* xn    = (u16*)(ws);                         // 8 MB  [T][D] bf16
    u16* w_bf  = (u16*)(ws + (size_t)(8u << 20));    // 24 MB [3D][D] bf16
    u16* o_bf  = (u16*)(ws + (size_t)(32u << 20));   // 8 MB  [D][D] bf16
    float* qkv = (float*)(ws + (size_t)(40u << 20)); // 48 MB [T][3D] fp32
    u16* q_bf  = (u16*)(ws + (size_t)(88u << 20));   // 8 MB  [h][T][hd]
    u16* k_bf  = (u16*)(ws + (size_t)(96u << 20));   // 8 MB
    u16* v_bf  = (u16*)(ws + (size_t)(104u << 20));  // 8 MB
    u16* x_bf  = (u16*)(ws + (size_t)(112u << 20));  // 8 MB  [T][D]

    cast_f32_bf16<<<6144, 256, 0, stream>>>(w_qkv, w_bf, 1572864);
    cast_f32_bf16<<<2048, 256, 0, stream>>>(w_o, o_bf, 524288);
    rmsnorm_row<<<2048, 256, 0, stream>>>(x_in, xn);
    gemm_bt<<<dim3(48, 16), 256, 0, stream>>>(xn, w_bf, qkv, nullptr, 2048, 6144, 2048);
    rope_split<<<2048, 256, 0, stream>>>(qkv, cosb, sinb, q_bf, k_bf, v_bf, k_out, v_out);
    attn_fwd<<<dim3(32, 16), 256, 0, stream>>>(q_bf, k_bf, v_bf, x_bf);
    gemm_bt<<<dim3(16, 16), 256, 0, stream>>>(x_bf, o_bf, out, x_in, 2048, 2048, 2048);
}

// Round 2
// 257.887 us; speedup vs baseline: 1.4477x; 1.4477x over previous
//
#include <hip/hip_runtime.h>
#include <hip/hip_bf16.h>

typedef unsigned short u16;
typedef unsigned int u32;
typedef __bf16 bf16x8 __attribute__((ext_vector_type(8)));
typedef u16 u16x8 __attribute__((ext_vector_type(8)));
typedef u16 u16x4 __attribute__((ext_vector_type(4)));
typedef float f32x4 __attribute__((ext_vector_type(4)));

#define T_SEQ 2048
#define DMODEL 2048
#define NHEAD 16
#define HDIM 128
#define ATT_SCALE 0.08838834764831843f

__device__ __forceinline__ u16 f2bf(float f) {
    return __builtin_bit_cast(u16, __float2bfloat16(f));
}
__device__ __forceinline__ bf16x8 as_bf(u16x8 v) {
    return __builtin_bit_cast(bf16x8, v);
}
// async global->LDS, 16B per lane. LDS dest must be linear in lane order.
__device__ __forceinline__ void gload_lds16(const u16* g, u16* l) {
    __builtin_amdgcn_global_load_lds(
        (const __attribute__((address_space(1))) u32*)(g),
        (__attribute__((address_space(3))) u32*)(l), 16, 0, 0);
}

// ---------------- cast fp32 -> bf16 (8 elems / thread) ----------------
__global__ __launch_bounds__(256) void cast_f32_bf16(const float* __restrict__ src,
                                                     u16* __restrict__ dst, int n8) {
    int i = blockIdx.x * 256 + threadIdx.x;
    if (i >= n8) return;
    float4 a = ((const float4*)src)[2 * i];
    float4 b = ((const float4*)src)[2 * i + 1];
    u16x8 o;
    o[0] = f2bf(a.x); o[1] = f2bf(a.y); o[2] = f2bf(a.z); o[3] = f2bf(a.w);
    o[4] = f2bf(b.x); o[5] = f2bf(b.y); o[6] = f2bf(b.z); o[7] = f2bf(b.w);
    *(u16x8*)(dst + (size_t)i * 8) = o;
}

// ---------------- row RMSNorm over D=2048, write bf16 ----------------
__global__ __launch_bounds__(256) void rmsnorm_row(const float* __restrict__ x,
                                                   u16* __restrict__ xn) {
    const int row = blockIdx.x, tid = threadIdx.x;
    const float* xr = x + (size_t)row * DMODEL;
    float4 a = ((const float4*)xr)[2 * tid];
    float4 b = ((const float4*)xr)[2 * tid + 1];
    float ss = a.x*a.x + a.y*a.y + a.z*a.z + a.w*a.w
             + b.x*b.x + b.y*b.y + b.z*b.z + b.w*b.w;
#pragma unroll
    for (int off = 32; off; off >>= 1) ss += __shfl_xor(ss, off);
    __shared__ float red[4];
    if ((tid & 63) == 0) red[tid >> 6] = ss;
    __syncthreads();
    float tot = red[0] + red[1] + red[2] + red[3];
    float r = rsqrtf(tot * (1.f / DMODEL) + 1e-6f);
    u16x8 o;
    o[0] = f2bf(a.x*r); o[1] = f2bf(a.y*r); o[2] = f2bf(a.z*r); o[3] = f2bf(a.w*r);
    o[4] = f2bf(b.x*r); o[5] = f2bf(b.y*r); o[6] = f2bf(b.z*r); o[7] = f2bf(b.w*r);
    *(u16x8*)(xn + (size_t)row * DMODEL + tid * 8) = o;
}

// ---------------- GEMM: C[m][n] = sum_k A[m][k]*B[n][k] (+resid) ----------------
// 128x128 tile, BK=32, 256 threads = 4 waves, global_load_lds staging (m97 form).
__global__ __launch_bounds__(256) void gemm_bt(const u16* __restrict__ A,
                                               const u16* __restrict__ B,
                                               float* __restrict__ C,
                                               const float* __restrict__ resid,
                                               int M, int N, int K) {
    __shared__ u16 As[128 * 32];
    __shared__ u16 Bs[128 * 32];
    const int bm = blockIdx.y * 128, bn = blockIdx.x * 128;
    const int tid = threadIdx.x, lane = tid & 63, wid = tid >> 6;
    const int wr = (wid >> 1) * 64, wc = (wid & 1) * 64;
    const int fr = lane & 15, fc = (lane >> 4) * 8;

    f32x4 acc[4][4] = {};

    // chunk idx -> LDS byte idx*16 -> As[row=idx>>2][col=(idx&3)*8] (linear in lane order)
    const int r0 = tid >> 2, c0 = (tid & 3) << 3;
    const u16* a0p = A + (size_t)(bm + r0) * K + c0;
    const u16* a1p = A + (size_t)(bm + r0 + 64) * K + c0;
    const u16* b0p = B + (size_t)(bn + r0) * K + c0;
    const u16* b1p = B + (size_t)(bn + r0 + 64) * K + c0;
    u16* la0 = As + (size_t)tid * 8;
    u16* la1 = As + (size_t)(tid + 256) * 8;
    u16* lb0 = Bs + (size_t)tid * 8;
    u16* lb1 = Bs + (size_t)(tid + 256) * 8;

    for (int k0 = 0; k0 < K; k0 += 32) {
        gload_lds16(a0p + k0, la0);
        gload_lds16(a1p + k0, la1);
        gload_lds16(b0p + k0, lb0);
        gload_lds16(b1p + k0, lb1);
        __syncthreads();   // drains vmcnt before barrier

        u16x8 af[4], bfm[4];
#pragma unroll
        for (int m = 0; m < 4; ++m)
            af[m] = *(const u16x8*)&As[(wr + m * 16 + fr) * 32 + fc];
#pragma unroll
        for (int n = 0; n < 4; ++n)
            bfm[n] = *(const u16x8*)&Bs[(wc + n * 16 + fr) * 32 + fc];
#pragma unroll
        for (int m = 0; m < 4; ++m)
#pragma unroll
            for (int n = 0; n < 4; ++n)
                acc[m][n] = __builtin_amdgcn_mfma_f32_16x16x32_bf16(
                    as_bf(af[m]), as_bf(bfm[n]), acc[m][n], 0, 0, 0);
        __syncthreads();
    }

#pragma unroll
    for (int m = 0; m < 4; ++m)
#pragma unroll
        for (int n = 0; n < 4; ++n)
#pragma unroll
            for (int r = 0; r < 4; ++r) {
                int row = bm + wr + m * 16 + (lane >> 4) * 4 + r;
                int col = bn + wc + n * 16 + fr;
                float val = acc[m][n][r];
                if (resid) val += resid[(size_t)row * N + col];
                C[(size_t)row * N + col] = val;
            }
}

// ---------------- per-head RMSNorm + RoPE for q,k; v passthrough ----------------
__global__ __launch_bounds__(256) void rope_split(const float* __restrict__ qkv,
                                                  const float* __restrict__ cosb,
                                                  const float* __restrict__ sinb,
                                                  u16* __restrict__ q_bf,
                                                  u16* __restrict__ k_bf,
                                                  float* __restrict__ k_out,
                                                  float* __restrict__ v_out) {
    const int t = blockIdx.x, tid = threadIdx.x, wid = tid >> 6, lane = tid & 63;
    const float* row = qkv + (size_t)t * (3 * DMODEL);
    const float c = cosb[t * 64 + lane];
    const float s = sinb[t * 64 + lane];

    for (int task = wid; task < 32; task += 4) {
        float x1 = row[task * 128 + lane];
        float x2 = row[task * 128 + 64 + lane];
        float ss = x1 * x1 + x2 * x2;
#pragma unroll
        for (int off = 32; off; off >>= 1) ss += __shfl_xor(ss, off);
        float r = rsqrtf(ss * (1.f / 128.f) + 1e-6f);
        float n1 = x1 * r, n2 = x2 * r;
        float o1 = n1 * c - n2 * s;
        float o2 = n1 * s + n2 * c;
        if (task < 16) {
            size_t base = ((size_t)task * T_SEQ + t) * 128 + lane;
            q_bf[base] = f2bf(o1);
            q_bf[base + 64] = f2bf(o2);
        } else {
            int hh = task - 16;
            size_t base = ((size_t)hh * T_SEQ + t) * 128 + lane;
            k_bf[base] = f2bf(o1);
            k_bf[base + 64] = f2bf(o2);
            size_t ob = (size_t)t * DMODEL + hh * 128 + lane;
            k_out[ob] = o1;
            k_out[ob + 64] = o2;
        }
    }
    for (int i = tid; i < DMODEL; i += 256) {
        v_out[(size_t)t * DMODEL + i] = row[2 * DMODEL + i];
    }
}

// ---------------- V transpose: qkv v-slice fp32 [T][...] -> vt bf16 [h][128][T] ----
// Per thread: fixed d, 8 consecutive t. Reads coalesced (lanes span consecutive d).
__global__ __launch_bounds__(256) void vtrans(const float* __restrict__ qkv,
                                              u16* __restrict__ vt) {
    const int b = blockIdx.x, tid = threadIdx.x;
    const int head = b >> 7;
    const int i = (b & 127) * 256 + tid;        // [0, 32768)
    const int d = i & 127, tc = i >> 7;         // tc in [0,256)
    u16x8 o;
#pragma unroll
    for (int j = 0; j < 8; ++j) {
        float v = qkv[(size_t)(tc * 8 + j) * (3 * DMODEL) + 2 * DMODEL + head * 128 + d];
        o[j] = f2bf(v);
    }
    *(u16x8*)&vt[((size_t)head * 128 + d) * T_SEQ + tc * 8] = o;
}

// ---------------- causal flash attention ----------------
// grid (T/64, h), 4 waves, QBLK=64 (16 q-rows/wave), KVBLK=64.
// K LDS [64][128] + Vt LDS [128][64] + per-wave P [16][64], all XOR-swizzled
// (byte ^= (row&7)<<4) so ds_read_b128/ds_write are bank-balanced (T2/G4).
__global__ __launch_bounds__(256) void attn_fwd(const u16* __restrict__ qb,
                                                const u16* __restrict__ kb,
                                                const u16* __restrict__ vtb,
                                                u16* __restrict__ xout) {
    __shared__ u16 Ks[64 * 128];
    __shared__ u16 Vs[128 * 64];
    __shared__ u16 Ps[4][16 * 64];

    const int qt = gridDim.x - 1 - blockIdx.x;   // long blocks dispatch first
    const int head = blockIdx.y;
    const int tid = threadIdx.x, wid = tid >> 6, lane = tid & 63;
    const int fr = lane & 15, fg = lane >> 4;
    const u16* kh = kb + (size_t)head * T_SEQ * 128;
    const u16* vth = vtb + (size_t)head * 128 * T_SEQ;
    const u16* qh = qb + (size_t)head * T_SEQ * 128;
    const int q0 = qt * 64 + wid * 16;
    const int qrow_g = q0 + fr;
    char* ksb = (char*)Ks;
    char* vsb = (char*)Vs;
    char* psb = (char*)&Ps[wid][0];

    u16x8 bq[4];
    {
        const u16* qrow = qh + (size_t)(q0 + fr) * 128 + fg * 8;
#pragma unroll
        for (int cc = 0; cc < 4; ++cc) bq[cc] = *(const u16x8*)(qrow + cc * 32);
    }

    f32x4 o[8] = {};
    float m_run = -1e30f, l_run = 0.f;
    const int nt = qt + 1;

    for (int kt = 0; kt < nt; ++kt) {
        const int kv0 = kt * 64;
        // stage K [64 rows x 256B] : 1024 16B-chunks, 4/thread, swizzled write
#pragma unroll
        for (int i = 0; i < 4; ++i) {
            int idx = i * 256 + tid;
            int r = idx >> 4, cb = (idx & 15) << 4;
            u16x8 kd = *(const u16x8*)(kh + (size_t)(kv0 + r) * 128 + (cb >> 1));
            *(u16x8*)(ksb + r * 256 + (cb ^ ((r & 7) << 4))) = kd;
        }
        // stage V^T [128 rows x 128B] : 1024 16B-chunks, 4/thread
#pragma unroll
        for (int i = 0; i < 4; ++i) {
            int idx = i * 256 + tid;
            int d = idx >> 3, cb = (idx & 7) << 4;
            u16x8 vd = *(const u16x8*)(vth + (size_t)d * T_SEQ + kv0 + (cb >> 1));
            *(u16x8*)(vsb + d * 128 + (cb ^ ((d & 7) << 4))) = vd;
        }
        __syncthreads();

        // S^T = K . Q^T : 4 kv sub-tiles of 16
        float p[4][4];
        float mx = -1e30f;
        const bool diag = (kv0 + 64 > q0);
#pragma unroll
        for (int st = 0; st < 4; ++st) {
            f32x4 sacc = {0.f, 0.f, 0.f, 0.f};
#pragma unroll
            for (int c4 = 0; c4 < 4; ++c4) {
                int r = st * 16 + fr;
                int cb = c4 * 64 + fg * 16;
                u16x8 ak = *(const u16x8*)(ksb + r * 256 + (cb ^ ((r & 7) << 4)));
                sacc = __builtin_amdgcn_mfma_f32_16x16x32_bf16(
                    as_bf(ak), as_bf(bq[c4]), sacc, 0, 0, 0);
            }
#pragma unroll
            for (int rr = 0; rr < 4; ++rr) {
                float sv = sacc[rr] * ATT_SCALE;
                if (diag) {
                    int kvg = kv0 + st * 16 + fg * 4 + rr;
                    sv = (kvg <= qrow_g) ? sv : -1e30f;
                }
                p[st][rr] = sv;
                mx = fmaxf(mx, sv);
            }
        }
        mx = fmaxf(mx, __shfl_xor(mx, 16));
        mx = fmaxf(mx, __shfl_xor(mx, 32));
        float m_new = fmaxf(m_run, mx);
        float corr = __expf(m_run - m_new);
        float rs = 0.f;
#pragma unroll
        for (int st = 0; st < 4; ++st) {
            u16x4 pw;
#pragma unroll
            for (int rr = 0; rr < 4; ++rr) {
                float e = __expf(p[st][rr] - m_new);
                rs += e;
                pw[rr] = f2bf(e);
            }
            *(u16x4*)(psb + fr * 128 + ((st * 32 + fg * 8) ^ ((fr & 7) << 4))) = pw;
        }
        rs += __shfl_xor(rs, 16);
        rs += __shfl_xor(rs, 32);
        l_run = l_run * corr + rs;
        m_run = m_new;

        // rescale O (corr of q-row fg*4+rr lives in lane fr==fg*4+rr)
        float ct[4];
#pragma unroll
        for (int rr = 0; rr < 4; ++rr) ct[rr] = __shfl(corr, fg * 4 + rr);
#pragma unroll
        for (int f = 0; f < 8; ++f)
#pragma unroll
            for (int rr = 0; rr < 4; ++rr) o[f][rr] *= ct[rr];

        // PV: O[q][d] += P[q][kv] * V^T[d][kv]   (same-wave LDS RAW on P is in-order)
#pragma unroll
        for (int ks = 0; ks < 2; ++ks) {
            u16x8 pa = *(const u16x8*)(psb + fr * 128 + ((ks * 64 + fg * 16) ^ ((fr & 7) << 4)));
#pragma unroll
            for (int f = 0; f < 8; ++f) {
                int d = f * 16 + fr;
                u16x8 vB = *(const u16x8*)(vsb + d * 128 + ((ks * 64 + fg * 16) ^ ((d & 7) << 4)));
                o[f] = __builtin_amdgcn_mfma_f32_16x16x32_bf16(
                    as_bf(pa), as_bf(vB), o[f], 0, 0, 0);
            }
        }
        __syncthreads();
    }

    float li[4];
#pragma unroll
    for (int rr = 0; rr < 4; ++rr) li[rr] = __shfl(l_run, fg * 4 + rr);
#pragma unroll
    for (int f = 0; f < 8; ++f)
#pragma unroll
        for (int rr = 0; rr < 4; ++rr) {
            int trow = q0 + fg * 4 + rr;
            float val = o[f][rr] / li[rr];
            xout[(size_t)trow * DMODEL + head * 128 + f * 16 + fr] = f2bf(val);
        }
}

extern "C" void kernel_launch(void* const* d_in, const int* in_sizes, int n_in,
                              void* d_out, int out_size, void* d_ws, size_t ws_size,
                              hipStream_t stream) {
    const float* x_in = (const float*)d_in[0];
    const float* w_qkv = (const float*)d_in[1];
    const float* w_o = (const float*)d_in[2];
    const float* cosb = (const float*)d_in[3];
    const float* sinb = (const float*)d_in[4];

    float* out = (float*)d_out;
    float* k_out = out + 4194304;
    float* v_out = out + 8388608;

    char* ws = (char*)d_ws;
    u16* xn    = (u16*)(ws);                         // 8 MiB  [T][D] bf16
    u16* w_bf  = (u16*)(ws + (size_t)(8u << 20));    // 24 MiB [3D][D] bf16
    u16* o_bf  = (u16*)(ws + (size_t)(32u << 20));   // 8 MiB  [D][D] bf16
    float* qkv = (float*)(ws + (size_t)(40u << 20)); // 48 MiB [T][3D] fp32
    u16* q_bf  = (u16*)(ws + (size_t)(88u << 20));   // 8 MiB  [h][T][hd]
    u16* k_bf  = (u16*)(ws + (size_t)(96u << 20));   // 8 MiB
    u16* vt_bf = (u16*)(ws + (size_t)(104u << 20));  // 8 MiB  [h][hd][T]
    u16* x_bf  = (u16*)(ws + (size_t)(112u << 20));  // 8 MiB  [T][D]

    cast_f32_bf16<<<6144, 256, 0, stream>>>(w_qkv, w_bf, 1572864);
    cast_f32_bf16<<<2048, 256, 0, stream>>>(w_o, o_bf, 524288);
    rmsnorm_row<<<2048, 256, 0, stream>>>(x_in, xn);
    gemm_bt<<<dim3(48, 16), 256, 0, stream>>>(xn, w_bf, qkv, nullptr, 2048, 6144, 2048);
    rope_split<<<2048, 256, 0, stream>>>(qkv, cosb, sinb, q_bf, k_bf, k_out, v_out);
    vtrans<<<2048, 256, 0, stream>>>(qkv, vt_bf);
    attn_fwd<<<dim3(32, 16), 256, 0, stream>>>(q_bf, k_bf, vt_bf, x_bf);
    gemm_bt<<<dim3(16, 16), 256, 0, stream>>>(x_bf, o_bf, out, x_in, 2048, 2048, 2048);
}

// Round 3
// 237.387 us; speedup vs baseline: 1.5727x; 1.0864x over previous
//
#include <hip/hip_runtime.h>
#include <hip/hip_bf16.h>

typedef unsigned short u16;
typedef unsigned int u32;
typedef __bf16 bf16x8 __attribute__((ext_vector_type(8)));
typedef u16 u16x8 __attribute__((ext_vector_type(8)));
typedef u16 u16x4 __attribute__((ext_vector_type(4)));
typedef float f32x4 __attribute__((ext_vector_type(4)));

#define T_SEQ 2048
#define DMODEL 2048
#define NHEAD 16
#define HDIM 128
#define ATT_SCALE 0.08838834764831843f

__device__ __forceinline__ u16 f2bf(float f) {
    return __builtin_bit_cast(u16, __float2bfloat16(f));
}
__device__ __forceinline__ bf16x8 as_bf(u16x8 v) {
    return __builtin_bit_cast(bf16x8, v);
}
__device__ __forceinline__ void gload_lds16(const u16* g, u16* l) {
    __builtin_amdgcn_global_load_lds(
        (const __attribute__((address_space(1))) u32*)(g),
        (__attribute__((address_space(3))) u32*)(l), 16, 0, 0);
}

// ---------------- cast fp32 -> bf16 ----------------
__global__ __launch_bounds__(256) void cast_f32_bf16(const float* __restrict__ src,
                                                     u16* __restrict__ dst, int n8) {
    int i = blockIdx.x * 256 + threadIdx.x;
    if (i >= n8) return;
    float4 a = ((const float4*)src)[2 * i];
    float4 b = ((const float4*)src)[2 * i + 1];
    u16x8 o;
    o[0] = f2bf(a.x); o[1] = f2bf(a.y); o[2] = f2bf(a.z); o[3] = f2bf(a.w);
    o[4] = f2bf(b.x); o[5] = f2bf(b.y); o[6] = f2bf(b.z); o[7] = f2bf(b.w);
    *(u16x8*)(dst + (size_t)i * 8) = o;
}

// ---------------- row RMSNorm ----------------
__global__ __launch_bounds__(256) void rmsnorm_row(const float* __restrict__ x,
                                                   u16* __restrict__ xn) {
    const int row = blockIdx.x, tid = threadIdx.x;
    const float* xr = x + (size_t)row * DMODEL;
    float4 a = ((const float4*)xr)[2 * tid];
    float4 b = ((const float4*)xr)[2 * tid + 1];
    float ss = a.x*a.x + a.y*a.y + a.z*a.z + a.w*a.w
             + b.x*b.x + b.y*b.y + b.z*b.z + b.w*b.w;
#pragma unroll
    for (int off = 32; off; off >>= 1) ss += __shfl_xor(ss, off);
    __shared__ float red[4];
    if ((tid & 63) == 0) red[tid >> 6] = ss;
    __syncthreads();
    float tot = red[0] + red[1] + red[2] + red[3];
    float r = rsqrtf(tot * (1.f / DMODEL) + 1e-6f);
    u16x8 o;
    o[0] = f2bf(a.x*r); o[1] = f2bf(a.y*r); o[2] = f2bf(a.z*r); o[3] = f2bf(a.w*r);
    o[4] = f2bf(b.x*r); o[5] = f2bf(b.y*r); o[6] = f2bf(b.z*r); o[7] = f2bf(b.w*r);
    *(u16x8*)(xn + (size_t)row * DMODEL + tid * 8) = o;
}

// ---------------- 128x128 m97-style GEMM (used for out-proj) ----------------
__global__ __launch_bounds__(256) void gemm_bt(const u16* __restrict__ A,
                                               const u16* __restrict__ B,
                                               float* __restrict__ C,
                                               const float* __restrict__ resid,
                                               int M, int N, int K) {
    __shared__ u16 As[128 * 32];
    __shared__ u16 Bs[128 * 32];
    const int bm = blockIdx.y * 128, bn = blockIdx.x * 128;
    const int tid = threadIdx.x, lane = tid & 63, wid = tid >> 6;
    const int wr = (wid >> 1) * 64, wc = (wid & 1) * 64;
    const int fr = lane & 15, fc = (lane >> 4) * 8;

    f32x4 acc[4][4] = {};
    const int r0 = tid >> 2, c0 = (tid & 3) << 3;
    const u16* a0p = A + (size_t)(bm + r0) * K + c0;
    const u16* a1p = A + (size_t)(bm + r0 + 64) * K + c0;
    const u16* b0p = B + (size_t)(bn + r0) * K + c0;
    const u16* b1p = B + (size_t)(bn + r0 + 64) * K + c0;
    u16* la0 = As + (size_t)tid * 8;
    u16* la1 = As + (size_t)(tid + 256) * 8;
    u16* lb0 = Bs + (size_t)tid * 8;
    u16* lb1 = Bs + (size_t)(tid + 256) * 8;

    for (int k0 = 0; k0 < K; k0 += 32) {
        gload_lds16(a0p + k0, la0);
        gload_lds16(a1p + k0, la1);
        gload_lds16(b0p + k0, lb0);
        gload_lds16(b1p + k0, lb1);
        __syncthreads();

        u16x8 af[4], bfm[4];
#pragma unroll
        for (int m = 0; m < 4; ++m)
            af[m] = *(const u16x8*)&As[(wr + m * 16 + fr) * 32 + fc];
#pragma unroll
        for (int n = 0; n < 4; ++n)
            bfm[n] = *(const u16x8*)&Bs[(wc + n * 16 + fr) * 32 + fc];
#pragma unroll
        for (int m = 0; m < 4; ++m)
#pragma unroll
            for (int n = 0; n < 4; ++n)
                acc[m][n] = __builtin_amdgcn_mfma_f32_16x16x32_bf16(
                    as_bf(af[m]), as_bf(bfm[n]), acc[m][n], 0, 0, 0);
        __syncthreads();
    }

#pragma unroll
    for (int m = 0; m < 4; ++m)
#pragma unroll
        for (int n = 0; n < 4; ++n)
#pragma unroll
            for (int r = 0; r < 4; ++r) {
                int row = bm + wr + m * 16 + (lane >> 4) * 4 + r;
                int col = bn + wc + n * 16 + fr;
                float val = acc[m][n][r];
                if (resid) val += resid[(size_t)row * N + col];
                C[(size_t)row * N + col] = val;
            }
}

// ---------------- 256x256 8-phase GEMM (qkv projection) ----------------
// BM=BN=256, BK=64, 512 threads (8 waves, 2Mx4N), dbuf LDS 128 KiB.
// T2: XOR-swizzle c16 ^= (row&7) applied via pre-swizzled global src (linear
// gload_lds dest) + swizzled ds_read. T3/T4: per-phase half-tile staging,
// vmcnt(4) only at phase 3/7. T5: setprio around MFMA cluster.
#define VM4 asm volatile("s_waitcnt vmcnt(4)" ::: "memory");
#define VM0 asm volatile("s_waitcnt vmcnt(0)" ::: "memory");

__device__ __forceinline__ void loadfrags(const u16* Ab, const u16* Bb,
                                          int mh, int nh, int wr, int wc,
                                          int fr, int fg,
                                          u16x8 av[4][2], u16x8 bv[2][2]) {
#pragma unroll
    for (int mq = 0; mq < 4; ++mq) {
        int ra = wr + mh * 64 + mq * 16 + fr;
        int sw = ra & 7;
#pragma unroll
        for (int k2 = 0; k2 < 2; ++k2) {
            int c16 = (k2 << 2) | fg;
            av[mq][k2] = *(const u16x8*)(Ab + ra * 64 + ((c16 ^ sw) << 3));
        }
    }
#pragma unroll
    for (int nq = 0; nq < 2; ++nq) {
        int rb = wc + nh * 32 + nq * 16 + fr;
        int sw = rb & 7;
#pragma unroll
        for (int k2 = 0; k2 < 2; ++k2) {
            int c16 = (k2 << 2) | fg;
            bv[nq][k2] = *(const u16x8*)(Bb + rb * 64 + ((c16 ^ sw) << 3));
        }
    }
}

#define PHASE(BUF, MH, NH, STAGE_STMT, VM_STMT)                               \
  {                                                                           \
    u16x8 av[4][2], bv[2][2];                                                 \
    loadfrags(sA[BUF], sB[BUF], MH, NH, wr, wc, fr, fg, av, bv);              \
    STAGE_STMT                                                                \
    __builtin_amdgcn_s_barrier();                                             \
    __builtin_amdgcn_s_setprio(1);                                            \
    _Pragma("unroll") for (int mq = 0; mq < 4; ++mq)                          \
      _Pragma("unroll") for (int nq = 0; nq < 2; ++nq)                        \
        _Pragma("unroll") for (int k2 = 0; k2 < 2; ++k2)                      \
          acc[(MH)*4+mq][(NH)*2+nq] = __builtin_amdgcn_mfma_f32_16x16x32_bf16(\
              as_bf(av[mq][k2]), as_bf(bv[nq][k2]),                           \
              acc[(MH)*4+mq][(NH)*2+nq], 0, 0, 0);                            \
    __builtin_amdgcn_s_setprio(0);                                            \
    VM_STMT                                                                   \
    __builtin_amdgcn_s_barrier();                                             \
    __builtin_amdgcn_sched_barrier(0);                                        \
  }

__global__ __launch_bounds__(512) void gemm256(const u16* __restrict__ A,
                                               const u16* __restrict__ B,
                                               float* __restrict__ C,
                                               int M, int N, int K) {
    extern __shared__ char smem[];
    const int tid = threadIdx.x, lane = tid & 63, wid = tid >> 6;
    const int bm = blockIdx.y * 256, bn = blockIdx.x * 256;
    const int wr = (wid >> 2) * 128, wc = (wid & 3) * 64;
    const int fr = lane & 15, fg = lane >> 4;

    u16* sA[2] = {(u16*)smem, (u16*)(smem + 65536)};
    u16* sB[2] = {(u16*)(smem + 32768), (u16*)(smem + 98304)};

    // staging per-thread constants
    const int cs = (((tid & 7) ^ ((tid >> 3) & 7)) << 3); // swizzled col (elems)
    const int s8 = (tid & 7) << 3;                        // linear LDS col (elems)
    const int rr6 = tid >> 3;                             // A row 0..63
    const int rb0 = ((tid >> 8) << 6) + ((tid >> 3) & 31);// B row base

    auto stA = [&](int buf, int k0, int mh) {
#pragma unroll
        for (int j = 0; j < 2; ++j) {
            int r = j * 128 + mh * 64 + rr6;
            gload_lds16(A + (size_t)(bm + r) * K + k0 + cs, sA[buf] + r * 64 + s8);
        }
    };
    auto stB = [&](int buf, int k0, int nh) {
#pragma unroll
        for (int j = 0; j < 2; ++j) {
            int r = j * 128 + nh * 32 + rb0;
            gload_lds16(B + (size_t)(bn + r) * K + k0 + cs, sB[buf] + r * 64 + s8);
        }
    };

    f32x4 acc[8][4] = {};
    const int nt = K >> 6;

    // prologue: tile0 full -> buf0 ; tile1 A-mh0,B-nh0 -> buf1
    stA(0, 0, 0); stA(0, 0, 1); stB(0, 0, 0); stB(0, 0, 1);
    stA(1, 64, 0); stB(1, 64, 0);
    VM4
    __builtin_amdgcn_s_barrier();
    __builtin_amdgcn_sched_barrier(0);

    for (int it = 0; it < (nt >> 1); ++it) {
        const int kc = it << 7;
        const int kn1 = kc + 64, kn2 = kc + 128, kn3 = kc + 192;
        const bool st2 = (kn2 < K), st3 = (kn3 < K);

        PHASE(0, 0, 0, { stA(1, kn1, 1); }, )
        PHASE(0, 0, 1, { stB(1, kn1, 1); }, )
        PHASE(0, 1, 0, { if (st2) stA(0, kn2, 0); }, )
        PHASE(0, 1, 1, { if (st2) stB(0, kn2, 0); }, if (st2) { VM4 } else { VM0 })
        PHASE(1, 0, 0, { if (st2) stA(0, kn2, 1); }, )
        PHASE(1, 0, 1, { if (st2) stB(0, kn2, 1); }, )
        PHASE(1, 1, 0, { if (st3) stA(1, kn3, 0); }, )
        PHASE(1, 1, 1, { if (st3) stB(1, kn3, 0); }, VM4)
    }

#pragma unroll
    for (int am = 0; am < 8; ++am)
#pragma unroll
        for (int bq = 0; bq < 4; ++bq)
#pragma unroll
            for (int r = 0; r < 4; ++r) {
                int row = bm + wr + am * 16 + fg * 4 + r;
                int col = bn + wc + bq * 16 + fr;
                C[(size_t)row * N + col] = acc[am][bq][r];
            }
}

// ---------------- per-head RMSNorm + RoPE for q,k; v passthrough ----------------
__global__ __launch_bounds__(256) void rope_split(const float* __restrict__ qkv,
                                                  const float* __restrict__ cosb,
                                                  const float* __restrict__ sinb,
                                                  u16* __restrict__ q_bf,
                                                  u16* __restrict__ k_bf,
                                                  float* __restrict__ k_out,
                                                  float* __restrict__ v_out) {
    const int t = blockIdx.x, tid = threadIdx.x, wid = tid >> 6, lane = tid & 63;
    const float* row = qkv + (size_t)t * (3 * DMODEL);
    const float c = cosb[t * 64 + lane];
    const float s = sinb[t * 64 + lane];

    for (int task = wid; task < 32; task += 4) {
        float x1 = row[task * 128 + lane];
        float x2 = row[task * 128 + 64 + lane];
        float ss = x1 * x1 + x2 * x2;
#pragma unroll
        for (int off = 32; off; off >>= 1) ss += __shfl_xor(ss, off);
        float r = rsqrtf(ss * (1.f / 128.f) + 1e-6f);
        float n1 = x1 * r, n2 = x2 * r;
        float o1 = n1 * c - n2 * s;
        float o2 = n1 * s + n2 * c;
        if (task < 16) {
            size_t base = ((size_t)task * T_SEQ + t) * 128 + lane;
            q_bf[base] = f2bf(o1);
            q_bf[base + 64] = f2bf(o2);
        } else {
            int hh = task - 16;
            size_t base = ((size_t)hh * T_SEQ + t) * 128 + lane;
            k_bf[base] = f2bf(o1);
            k_bf[base + 64] = f2bf(o2);
            size_t ob = (size_t)t * DMODEL + hh * 128 + lane;
            k_out[ob] = o1;
            k_out[ob + 64] = o2;
        }
    }
    for (int i = tid; i < DMODEL; i += 256) {
        v_out[(size_t)t * DMODEL + i] = row[2 * DMODEL + i];
    }
}

// ---------------- V transpose -> [h][128][T] bf16 ----------------
__global__ __launch_bounds__(256) void vtrans(const float* __restrict__ qkv,
                                              u16* __restrict__ vt) {
    const int b = blockIdx.x, tid = threadIdx.x;
    const int head = b >> 7;
    const int i = (b & 127) * 256 + tid;
    const int d = i & 127, tc = i >> 7;
    u16x8 o;
#pragma unroll
    for (int j = 0; j < 8; ++j) {
        float v = qkv[(size_t)(tc * 8 + j) * (3 * DMODEL) + 2 * DMODEL + head * 128 + d];
        o[j] = f2bf(v);
    }
    *(u16x8*)&vt[((size_t)head * 128 + d) * T_SEQ + tc * 8] = o;
}

// ---------------- causal flash attention ----------------
// 1-D grid of 512; work-balanced pairing: blocks b and b+256 (co-resident on
// the same CU under round-robin dispatch) get qt = 31-j and j -> 33 units/CU.
__global__ __launch_bounds__(256) void attn_fwd(const u16* __restrict__ qb,
                                                const u16* __restrict__ kb,
                                                const u16* __restrict__ vtb,
                                                u16* __restrict__ xout) {
    __shared__ u16 Ks[64 * 128];
    __shared__ u16 Vs[128 * 64];
    __shared__ u16 Ps[4][16 * 64];

    const int bid = blockIdx.x;
    const int half = bid >> 8, idx = bid & 255;
    const int head = (half << 3) | (idx >> 5);
    const int j = idx & 31;
    const int qt = half ? j : 31 - j;

    const int tid = threadIdx.x, wid = tid >> 6, lane = tid & 63;
    const int fr = lane & 15, fg = lane >> 4;
    const u16* kh = kb + (size_t)head * T_SEQ * 128;
    const u16* vth = vtb + (size_t)head * 128 * T_SEQ;
    const u16* qh = qb + (size_t)head * T_SEQ * 128;
    const int q0 = qt * 64 + wid * 16;
    const int qrow_g = q0 + fr;
    char* ksb = (char*)Ks;
    char* vsb = (char*)Vs;
    char* psb = (char*)&Ps[wid][0];

    u16x8 bq[4];
    {
        const u16* qrow = qh + (size_t)(q0 + fr) * 128 + fg * 8;
#pragma unroll
        for (int cc = 0; cc < 4; ++cc) bq[cc] = *(const u16x8*)(qrow + cc * 32);
    }

    f32x4 o[8] = {};
    float m_run = -1e30f, l_run = 0.f;
    const int nt = qt + 1;

    for (int kt = 0; kt < nt; ++kt) {
        const int kv0 = kt * 64;
#pragma unroll
        for (int i = 0; i < 4; ++i) {
            int idx2 = i * 256 + tid;
            int r = idx2 >> 4, cb = (idx2 & 15) << 4;
            u16x8 kd = *(const u16x8*)(kh + (size_t)(kv0 + r) * 128 + (cb >> 1));
            *(u16x8*)(ksb + r * 256 + (cb ^ ((r & 7) << 4))) = kd;
        }
#pragma unroll
        for (int i = 0; i < 4; ++i) {
            int idx2 = i * 256 + tid;
            int d = idx2 >> 3, cb = (idx2 & 7) << 4;
            u16x8 vd = *(const u16x8*)(vth + (size_t)d * T_SEQ + kv0 + (cb >> 1));
            *(u16x8*)(vsb + d * 128 + (cb ^ ((d & 7) << 4))) = vd;
        }
        __syncthreads();

        float p[4][4];
        float mx = -1e30f;
        const bool diag = (kv0 + 64 > q0);
#pragma unroll
        for (int st = 0; st < 4; ++st) {
            f32x4 sacc = {0.f, 0.f, 0.f, 0.f};
#pragma unroll
            for (int c4 = 0; c4 < 4; ++c4) {
                int r = st * 16 + fr;
                int cb = c4 * 64 + fg * 16;
                u16x8 ak = *(const u16x8*)(ksb + r * 256 + (cb ^ ((r & 7) << 4)));
                sacc = __builtin_amdgcn_mfma_f32_16x16x32_bf16(
                    as_bf(ak), as_bf(bq[c4]), sacc, 0, 0, 0);
            }
#pragma unroll
            for (int rr = 0; rr < 4; ++rr) {
                float sv = sacc[rr] * ATT_SCALE;
                if (diag) {
                    int kvg = kv0 + st * 16 + fg * 4 + rr;
                    sv = (kvg <= qrow_g) ? sv : -1e30f;
                }
                p[st][rr] = sv;
                mx = fmaxf(mx, sv);
            }
        }
        mx = fmaxf(mx, __shfl_xor(mx, 16));
        mx = fmaxf(mx, __shfl_xor(mx, 32));

        // T13 defer-max: skip rescale while tile max stays within e^8 headroom
        if (__all(mx - m_run <= 8.f)) {
            float rs = 0.f;
#pragma unroll
            for (int st = 0; st < 4; ++st) {
                u16x4 pw;
#pragma unroll
                for (int rr = 0; rr < 4; ++rr) {
                    float e = __expf(p[st][rr] - m_run);
                    rs += e;
                    pw[rr] = f2bf(e);
                }
                *(u16x4*)(psb + fr * 128 + ((st * 32 + fg * 8) ^ ((fr & 7) << 4))) = pw;
            }
            rs += __shfl_xor(rs, 16);
            rs += __shfl_xor(rs, 32);
            l_run += rs;
        } else {
            float m_new = fmaxf(m_run, mx);
            float corr = __expf(m_run - m_new);
            float rs = 0.f;
#pragma unroll
            for (int st = 0; st < 4; ++st) {
                u16x4 pw;
#pragma unroll
                for (int rr = 0; rr < 4; ++rr) {
                    float e = __expf(p[st][rr] - m_new);
                    rs += e;
                    pw[rr] = f2bf(e);
                }
                *(u16x4*)(psb + fr * 128 + ((st * 32 + fg * 8) ^ ((fr & 7) << 4))) = pw;
            }
            rs += __shfl_xor(rs, 16);
            rs += __shfl_xor(rs, 32);
            l_run = l_run * corr + rs;
            m_run = m_new;
            float ct[4];
#pragma unroll
            for (int rr = 0; rr < 4; ++rr) ct[rr] = __shfl(corr, fg * 4 + rr);
#pragma unroll
            for (int f = 0; f < 8; ++f)
#pragma unroll
                for (int rr = 0; rr < 4; ++rr) o[f][rr] *= ct[rr];
        }

#pragma unroll
        for (int ks = 0; ks < 2; ++ks) {
            u16x8 pa = *(const u16x8*)(psb + fr * 128 + ((ks * 64 + fg * 16) ^ ((fr & 7) << 4)));
#pragma unroll
            for (int f = 0; f < 8; ++f) {
                int d = f * 16 + fr;
                u16x8 vB = *(const u16x8*)(vsb + d * 128 + ((ks * 64 + fg * 16) ^ ((d & 7) << 4)));
                o[f] = __builtin_amdgcn_mfma_f32_16x16x32_bf16(
                    as_bf(pa), as_bf(vB), o[f], 0, 0, 0);
            }
        }
        __syncthreads();
    }

    float li[4];
#pragma unroll
    for (int rr = 0; rr < 4; ++rr) li[rr] = __shfl(l_run, fg * 4 + rr);
#pragma unroll
    for (int f = 0; f < 8; ++f)
#pragma unroll
        for (int rr = 0; rr < 4; ++rr) {
            int trow = q0 + fg * 4 + rr;
            float val = o[f][rr] / li[rr];
            xout[(size_t)trow * DMODEL + head * 128 + f * 16 + fr] = f2bf(val);
        }
}

extern "C" void kernel_launch(void* const* d_in, const int* in_sizes, int n_in,
                              void* d_out, int out_size, void* d_ws, size_t ws_size,
                              hipStream_t stream) {
    const float* x_in = (const float*)d_in[0];
    const float* w_qkv = (const float*)d_in[1];
    const float* w_o = (const float*)d_in[2];
    const float* cosb = (const float*)d_in[3];
    const float* sinb = (const float*)d_in[4];

    float* out = (float*)d_out;
    float* k_out = out + 4194304;
    float* v_out = out + 8388608;

    char* ws = (char*)d_ws;
    u16* xn    = (u16*)(ws);                         // 8 MiB  [T][D] bf16
    u16* w_bf  = (u16*)(ws + (size_t)(8u << 20));    // 24 MiB [3D][D] bf16
    u16* o_bf  = (u16*)(ws + (size_t)(32u << 20));   // 8 MiB  [D][D] bf16
    float* qkv = (float*)(ws + (size_t)(40u << 20)); // 48 MiB [T][3D] fp32
    u16* q_bf  = (u16*)(ws + (size_t)(88u << 20));   // 8 MiB  [h][T][hd]
    u16* k_bf  = (u16*)(ws + (size_t)(96u << 20));   // 8 MiB
    u16* vt_bf = (u16*)(ws + (size_t)(104u << 20));  // 8 MiB  [h][hd][T]
    u16* x_bf  = (u16*)(ws + (size_t)(112u << 20));  // 8 MiB  [T][D]

    (void)hipFuncSetAttribute(reinterpret_cast<const void*>(&gemm256),
                              hipFuncAttributeMaxDynamicSharedMemorySize, 131072);

    cast_f32_bf16<<<6144, 256, 0, stream>>>(w_qkv, w_bf, 1572864);
    cast_f32_bf16<<<2048, 256, 0, stream>>>(w_o, o_bf, 524288);
    rmsnorm_row<<<2048, 256, 0, stream>>>(x_in, xn);
    gemm256<<<dim3(24, 8), 512, 131072, stream>>>(xn, w_bf, qkv, 2048, 6144, 2048);
    rope_split<<<2048, 256, 0, stream>>>(qkv, cosb, sinb, q_bf, k_bf, k_out, v_out);
    vtrans<<<2048, 256, 0, stream>>>(qkv, vt_bf);
    attn_fwd<<<512, 256, 0, stream>>>(q_bf, k_bf, vt_bf, x_bf);
    gemm_bt<<<dim3(16, 16), 256, 0, stream>>>(x_bf, o_bf, out, x_in, 2048, 2048, 2048);
}

// Round 4
// 227.590 us; speedup vs baseline: 1.6404x; 1.0430x over previous
//
#include <hip/hip_runtime.h>
#include <hip/hip_bf16.h>

typedef unsigned short u16;
typedef unsigned int u32;
typedef __bf16 bf16x8 __attribute__((ext_vector_type(8)));
typedef u16 u16x8 __attribute__((ext_vector_type(8)));
typedef u16 u16x4 __attribute__((ext_vector_type(4)));
typedef float f32x4 __attribute__((ext_vector_type(4)));

#define T_SEQ 2048
#define DMODEL 2048
#define NHEAD 16
#define HDIM 128
#define ATT_SCALE 0.08838834764831843f

__device__ __forceinline__ u16 f2bf(float f) {
    return __builtin_bit_cast(u16, __float2bfloat16(f));
}
__device__ __forceinline__ bf16x8 as_bf(u16x8 v) {
    return __builtin_bit_cast(bf16x8, v);
}
__device__ __forceinline__ float lo2f(u32 w) { return __builtin_bit_cast(float, w << 16); }
__device__ __forceinline__ float hi2f(u32 w) { return __builtin_bit_cast(float, w & 0xffff0000u); }
__device__ __forceinline__ void gload_lds16(const u16* g, u16* l) {
    __builtin_amdgcn_global_load_lds(
        (const __attribute__((address_space(1))) u32*)(g),
        (__attribute__((address_space(3))) u32*)(l), 16, 0, 0);
}

// ---------------- fused weight casts fp32 -> bf16 ----------------
// w_qkv: 1572864 chunks of 8 ; w_o: 524288 chunks of 8.
__global__ __launch_bounds__(256) void cast_both(const float* __restrict__ w1,
                                                 const float* __restrict__ w2,
                                                 u16* __restrict__ d1,
                                                 u16* __restrict__ d2) {
    int i = blockIdx.x * 256 + threadIdx.x;
    const float* src; u16* dst; int k;
    if (i < 1572864) { src = w1; dst = d1; k = i; }
    else             { src = w2; dst = d2; k = i - 1572864; }
    float4 a = ((const float4*)src)[2 * k];
    float4 b = ((const float4*)src)[2 * k + 1];
    u16x8 o;
    o[0] = f2bf(a.x); o[1] = f2bf(a.y); o[2] = f2bf(a.z); o[3] = f2bf(a.w);
    o[4] = f2bf(b.x); o[5] = f2bf(b.y); o[6] = f2bf(b.z); o[7] = f2bf(b.w);
    *(u16x8*)(dst + (size_t)k * 8) = o;
}

// ---------------- row RMSNorm over D=2048, write bf16 ----------------
__global__ __launch_bounds__(256) void rmsnorm_row(const float* __restrict__ x,
                                                   u16* __restrict__ xn) {
    const int row = blockIdx.x, tid = threadIdx.x;
    const float* xr = x + (size_t)row * DMODEL;
    float4 a = ((const float4*)xr)[2 * tid];
    float4 b = ((const float4*)xr)[2 * tid + 1];
    float ss = a.x*a.x + a.y*a.y + a.z*a.z + a.w*a.w
             + b.x*b.x + b.y*b.y + b.z*b.z + b.w*b.w;
#pragma unroll
    for (int off = 32; off; off >>= 1) ss += __shfl_xor(ss, off);
    __shared__ float red[4];
    if ((tid & 63) == 0) red[tid >> 6] = ss;
    __syncthreads();
    float tot = red[0] + red[1] + red[2] + red[3];
    float r = rsqrtf(tot * (1.f / DMODEL) + 1e-6f);
    u16x8 o;
    o[0] = f2bf(a.x*r); o[1] = f2bf(a.y*r); o[2] = f2bf(a.z*r); o[3] = f2bf(a.w*r);
    o[4] = f2bf(b.x*r); o[5] = f2bf(b.y*r); o[6] = f2bf(b.z*r); o[7] = f2bf(b.w*r);
    *(u16x8*)(xn + (size_t)row * DMODEL + tid * 8) = o;
}

// ---------------- 128x128 m97-style GEMM (out-proj, fp32 C + resid) --------
__global__ __launch_bounds__(256) void gemm_bt(const u16* __restrict__ A,
                                               const u16* __restrict__ B,
                                               float* __restrict__ C,
                                               const float* __restrict__ resid,
                                               int M, int N, int K) {
    __shared__ u16 As[128 * 32];
    __shared__ u16 Bs[128 * 32];
    const int bm = blockIdx.y * 128, bn = blockIdx.x * 128;
    const int tid = threadIdx.x, lane = tid & 63, wid = tid >> 6;
    const int wr = (wid >> 1) * 64, wc = (wid & 1) * 64;
    const int fr = lane & 15, fc = (lane >> 4) * 8;

    f32x4 acc[4][4] = {};
    const int r0 = tid >> 2, c0 = (tid & 3) << 3;
    const u16* a0p = A + (size_t)(bm + r0) * K + c0;
    const u16* a1p = A + (size_t)(bm + r0 + 64) * K + c0;
    const u16* b0p = B + (size_t)(bn + r0) * K + c0;
    const u16* b1p = B + (size_t)(bn + r0 + 64) * K + c0;
    u16* la0 = As + (size_t)tid * 8;
    u16* la1 = As + (size_t)(tid + 256) * 8;
    u16* lb0 = Bs + (size_t)tid * 8;
    u16* lb1 = Bs + (size_t)(tid + 256) * 8;

    for (int k0 = 0; k0 < K; k0 += 32) {
        gload_lds16(a0p + k0, la0);
        gload_lds16(a1p + k0, la1);
        gload_lds16(b0p + k0, lb0);
        gload_lds16(b1p + k0, lb1);
        __syncthreads();

        u16x8 af[4], bfm[4];
#pragma unroll
        for (int m = 0; m < 4; ++m)
            af[m] = *(const u16x8*)&As[(wr + m * 16 + fr) * 32 + fc];
#pragma unroll
        for (int n = 0; n < 4; ++n)
            bfm[n] = *(const u16x8*)&Bs[(wc + n * 16 + fr) * 32 + fc];
#pragma unroll
        for (int m = 0; m < 4; ++m)
#pragma unroll
            for (int n = 0; n < 4; ++n)
                acc[m][n] = __builtin_amdgcn_mfma_f32_16x16x32_bf16(
                    as_bf(af[m]), as_bf(bfm[n]), acc[m][n], 0, 0, 0);
        __syncthreads();
    }

#pragma unroll
    for (int m = 0; m < 4; ++m)
#pragma unroll
        for (int n = 0; n < 4; ++n)
#pragma unroll
            for (int r = 0; r < 4; ++r) {
                int row = bm + wr + m * 16 + (lane >> 4) * 4 + r;
                int col = bn + wc + n * 16 + fr;
                float val = acc[m][n][r];
                if (resid) val += resid[(size_t)row * N + col];
                C[(size_t)row * N + col] = val;
            }
}

// ---------------- 256x256 8-phase GEMM (qkv projection, bf16 C) ------------
#define VM4 asm volatile("s_waitcnt vmcnt(4)" ::: "memory");
#define VM0 asm volatile("s_waitcnt vmcnt(0)" ::: "memory");

__device__ __forceinline__ void loadfrags(const u16* Ab, const u16* Bb,
                                          int mh, int nh, int wr, int wc,
                                          int fr, int fg,
                                          u16x8 av[4][2], u16x8 bv[2][2]) {
#pragma unroll
    for (int mq = 0; mq < 4; ++mq) {
        int ra = wr + mh * 64 + mq * 16 + fr;
        int sw = ra & 7;
#pragma unroll
        for (int k2 = 0; k2 < 2; ++k2) {
            int c16 = (k2 << 2) | fg;
            av[mq][k2] = *(const u16x8*)(Ab + ra * 64 + ((c16 ^ sw) << 3));
        }
    }
#pragma unroll
    for (int nq = 0; nq < 2; ++nq) {
        int rb = wc + nh * 32 + nq * 16 + fr;
        int sw = rb & 7;
#pragma unroll
        for (int k2 = 0; k2 < 2; ++k2) {
            int c16 = (k2 << 2) | fg;
            bv[nq][k2] = *(const u16x8*)(Bb + rb * 64 + ((c16 ^ sw) << 3));
        }
    }
}

#define PHASE(BUF, MH, NH, STAGE_STMT, VM_STMT)                               \
  {                                                                           \
    u16x8 av[4][2], bv[2][2];                                                 \
    loadfrags(sA[BUF], sB[BUF], MH, NH, wr, wc, fr, fg, av, bv);              \
    STAGE_STMT                                                                \
    __builtin_amdgcn_s_barrier();                                             \
    __builtin_amdgcn_s_setprio(1);                                            \
    _Pragma("unroll") for (int mq = 0; mq < 4; ++mq)                          \
      _Pragma("unroll") for (int nq = 0; nq < 2; ++nq)                        \
        _Pragma("unroll") for (int k2 = 0; k2 < 2; ++k2)                      \
          acc[(MH)*4+mq][(NH)*2+nq] = __builtin_amdgcn_mfma_f32_16x16x32_bf16(\
              as_bf(av[mq][k2]), as_bf(bv[nq][k2]),                           \
              acc[(MH)*4+mq][(NH)*2+nq], 0, 0, 0);                            \
    __builtin_amdgcn_s_setprio(0);                                            \
    VM_STMT                                                                   \
    __builtin_amdgcn_s_barrier();                                             \
    __builtin_amdgcn_sched_barrier(0);                                        \
  }

__global__ __launch_bounds__(512) void gemm256(const u16* __restrict__ A,
                                               const u16* __restrict__ B,
                                               u16* __restrict__ C,
                                               int M, int N, int K) {
    extern __shared__ char smem[];
    const int tid = threadIdx.x, lane = tid & 63, wid = tid >> 6;
    const int bm = blockIdx.y * 256, bn = blockIdx.x * 256;
    const int wr = (wid >> 2) * 128, wc = (wid & 3) * 64;
    const int fr = lane & 15, fg = lane >> 4;

    u16* sA[2] = {(u16*)smem, (u16*)(smem + 65536)};
    u16* sB[2] = {(u16*)(smem + 32768), (u16*)(smem + 98304)};

    const int cs = (((tid & 7) ^ ((tid >> 3) & 7)) << 3);
    const int s8 = (tid & 7) << 3;
    const int rr6 = tid >> 3;
    const int rb0 = ((tid >> 8) << 6) + ((tid >> 3) & 31);

    auto stA = [&](int buf, int k0, int mh) {
#pragma unroll
        for (int j = 0; j < 2; ++j) {
            int r = j * 128 + mh * 64 + rr6;
            gload_lds16(A + (size_t)(bm + r) * K + k0 + cs, sA[buf] + r * 64 + s8);
        }
    };
    auto stB = [&](int buf, int k0, int nh) {
#pragma unroll
        for (int j = 0; j < 2; ++j) {
            int r = j * 128 + nh * 32 + rb0;
            gload_lds16(B + (size_t)(bn + r) * K + k0 + cs, sB[buf] + r * 64 + s8);
        }
    };

    f32x4 acc[8][4] = {};
    const int nt = K >> 6;

    stA(0, 0, 0); stA(0, 0, 1); stB(0, 0, 0); stB(0, 0, 1);
    stA(1, 64, 0); stB(1, 64, 0);
    VM4
    __builtin_amdgcn_s_barrier();
    __builtin_amdgcn_sched_barrier(0);

    for (int it = 0; it < (nt >> 1); ++it) {
        const int kc = it << 7;
        const int kn1 = kc + 64, kn2 = kc + 128, kn3 = kc + 192;
        const bool st2 = (kn2 < K), st3 = (kn3 < K);

        PHASE(0, 0, 0, { stA(1, kn1, 1); }, )
        PHASE(0, 0, 1, { stB(1, kn1, 1); }, )
        PHASE(0, 1, 0, { if (st2) stA(0, kn2, 0); }, )
        PHASE(0, 1, 1, { if (st2) stB(0, kn2, 0); }, if (st2) { VM4 } else { VM0 })
        PHASE(1, 0, 0, { if (st2) stA(0, kn2, 1); }, )
        PHASE(1, 0, 1, { if (st2) stB(0, kn2, 1); }, )
        PHASE(1, 1, 0, { if (st3) stA(1, kn3, 0); }, )
        PHASE(1, 1, 1, { if (st3) stB(1, kn3, 0); }, VM4)
    }

#pragma unroll
    for (int am = 0; am < 8; ++am)
#pragma unroll
        for (int bq = 0; bq < 4; ++bq)
#pragma unroll
            for (int r = 0; r < 4; ++r) {
                int row = bm + wr + am * 16 + fg * 4 + r;
                int col = bn + wc + bq * 16 + fr;
                C[(size_t)row * N + col] = f2bf(acc[am][bq][r]);
            }
}

// ---------------- per-head RMSNorm + RoPE (vectorized, bf16 qkv) -----------
// Wave handles one head-vector: lane l holds dims {2l, 2l+1}; partner via
// shfl_xor(32). dim(l) = 2l for all l (lo half l<32, hi half l>=32).
__global__ __launch_bounds__(256) void rope_split(const u16* __restrict__ qkv,
                                                  const float* __restrict__ cosb,
                                                  const float* __restrict__ sinb,
                                                  u16* __restrict__ q_bf,
                                                  u16* __restrict__ k_bf,
                                                  float* __restrict__ k_out,
                                                  float* __restrict__ v_out) {
    const int t = blockIdx.x, tid = threadIdx.x, wid = tid >> 6, lane = tid & 63;
    const u16* row = qkv + (size_t)t * (3 * DMODEL);
    const int dp = (lane & 31) << 1;
    float2 c2 = *(const float2*)(cosb + t * 64 + dp);
    float2 s2 = *(const float2*)(sinb + t * 64 + dp);
    const bool hi = lane >= 32;

    for (int task = wid; task < 32; task += 4) {
        u32 w = *(const u32*)(row + task * 128 + lane * 2);
        float xa = lo2f(w), xb = hi2f(w);
        float ss = xa * xa + xb * xb;
#pragma unroll
        for (int off = 32; off; off >>= 1) ss += __shfl_xor(ss, off);
        float rn = rsqrtf(ss * (1.f / 128.f) + 1e-6f);
        float pa = __shfl_xor(xa, 32), pb = __shfl_xor(xb, 32);
        float oa, ob;
        if (!hi) {
            oa = (xa * c2.x - pa * s2.x) * rn;
            ob = (xb * c2.y - pb * s2.y) * rn;
        } else {
            oa = (pa * s2.x + xa * c2.x) * rn;
            ob = (pb * s2.y + xb * c2.y) * rn;
        }
        u32 pk = (u32)f2bf(oa) | ((u32)f2bf(ob) << 16);
        if (task < 16) {
            *(u32*)(q_bf + ((size_t)task * T_SEQ + t) * 128 + lane * 2) = pk;
        } else {
            int hh = task - 16;
            *(u32*)(k_bf + ((size_t)hh * T_SEQ + t) * 128 + lane * 2) = pk;
            float2 kk; kk.x = oa; kk.y = ob;
            *(float2*)(k_out + (size_t)t * DMODEL + hh * 128 + lane * 2) = kk;
        }
    }
    // v passthrough bf16 -> fp32
    {
        u16x8 vv = *(const u16x8*)(row + 2 * DMODEL + tid * 8);
        float4 f0, f1;
        f0.x = lo2f((u32)vv[0] << 16 >> 16 << 16 >> 16 | ((u32)vv[0]));  // placeholder avoided below
        f0.x = __builtin_bit_cast(float, (u32)vv[0] << 16);
        f0.y = __builtin_bit_cast(float, (u32)vv[1] << 16);
        f0.z = __builtin_bit_cast(float, (u32)vv[2] << 16);
        f0.w = __builtin_bit_cast(float, (u32)vv[3] << 16);
        f1.x = __builtin_bit_cast(float, (u32)vv[4] << 16);
        f1.y = __builtin_bit_cast(float, (u32)vv[5] << 16);
        f1.z = __builtin_bit_cast(float, (u32)vv[6] << 16);
        f1.w = __builtin_bit_cast(float, (u32)vv[7] << 16);
        *(float4*)(v_out + (size_t)t * DMODEL + tid * 8) = f0;
        *(float4*)(v_out + (size_t)t * DMODEL + tid * 8 + 4) = f1;
    }
}

// ---------------- V transpose: qkv bf16 -> vt bf16 [h][128][T] -------------
__global__ __launch_bounds__(256) void vtrans(const u16* __restrict__ qkv,
                                              u16* __restrict__ vt) {
    const int b = blockIdx.x, tid = threadIdx.x;
    const int head = b >> 7;
    const int i = (b & 127) * 256 + tid;
    const int d = i & 127, tc = i >> 7;
    u16x8 o;
#pragma unroll
    for (int j = 0; j < 8; ++j)
        o[j] = qkv[(size_t)(tc * 8 + j) * (3 * DMODEL) + 2 * DMODEL + head * 128 + d];
    *(u16x8*)&vt[((size_t)head * 128 + d) * T_SEQ + tc * 8] = o;
}

// ---------------- causal flash attention (pipelined staging) ---------------
// bid&7 = XCD residue -> each XCD serves heads {r, r+8} (KV L2-resident, 2MB).
// Pairing: bid and bid+256 share a CU: qt (31-j)+(j) -> 33 units.
// Staging: global_load_lds w=16, pre-swizzled global col + linear LDS dest;
// double-buffered; counted vmcnt(8) + raw s_barrier (no vmcnt(0) drain).
__global__ __launch_bounds__(256) void attn_fwd(const u16* __restrict__ qb,
                                                const u16* __restrict__ kb,
                                                const u16* __restrict__ vtb,
                                                u16* __restrict__ xout) {
    __shared__ u16 Ks[2][64 * 128];
    __shared__ u16 Vs[2][128 * 64];
    __shared__ u16 Ps[4][16 * 64];

    const int bid = blockIdx.x;
    const int r8 = bid & 7, s = bid >> 3;
    const int head = r8 + ((s >> 5) << 3);
    const int j = s & 31;
    const int qt = (s < 32) ? (31 - j) : j;

    const int tid = threadIdx.x, wid = tid >> 6, lane = tid & 63;
    const int fr = lane & 15, fg = lane >> 4;
    const u16* kh = kb + (size_t)head * T_SEQ * 128;
    const u16* vth = vtb + (size_t)head * 128 * T_SEQ;
    const u16* qh = qb + (size_t)head * T_SEQ * 128;
    const int q0 = qt * 64 + wid * 16;
    const int qrow_g = q0 + fr;

    u16x8 bq[4];
    {
        const u16* qrow = qh + (size_t)(q0 + fr) * 128 + fg * 8;
#pragma unroll
        for (int cc = 0; cc < 4; ++cc) bq[cc] = *(const u16x8*)(qrow + cc * 32);
    }

    // staging: K chunk idx -> r=idx>>4, swizzled col; V chunk idx -> d=idx>>3
    auto stage = [&](int kv0, int buf) {
#pragma unroll
        for (int i = 0; i < 4; ++i) {
            int idx = i * 256 + tid;
            int r = idx >> 4;
            int cbs = ((idx & 15) << 4) ^ ((r & 7) << 4);
            gload_lds16(kh + (size_t)(kv0 + r) * 128 + (cbs >> 1), &Ks[buf][idx * 8]);
        }
#pragma unroll
        for (int i = 0; i < 4; ++i) {
            int idx = i * 256 + tid;
            int d = idx >> 3;
            int cbs = ((idx & 7) << 4) ^ ((d & 7) << 4);
            gload_lds16(vth + (size_t)d * T_SEQ + kv0 + (cbs >> 1), &Vs[buf][idx * 8]);
        }
    };

    stage(0, 0);

    f32x4 o[8] = {};
    float m_run = -1e30f, l_run = 0.f;
    const int nt = qt + 1;

    for (int kt = 0; kt < nt; ++kt) {
        const int kv0 = kt * 64;
        const int buf = kt & 1;
        if (kt + 1 < nt) {
            stage(kv0 + 64, buf ^ 1);
            asm volatile("s_waitcnt vmcnt(8)" ::: "memory");
        } else {
            asm volatile("s_waitcnt vmcnt(0)" ::: "memory");
        }
        __builtin_amdgcn_s_barrier();
        __builtin_amdgcn_sched_barrier(0);

        const char* ksb = (const char*)&Ks[buf][0];
        const char* vsb = (const char*)&Vs[buf][0];
        char* psb = (char*)&Ps[wid][0];

        float p[4][4];
        float mx = -1e30f;
        const bool diag = (kv0 + 64 > q0);
#pragma unroll
        for (int st = 0; st < 4; ++st) {
            f32x4 sacc = {0.f, 0.f, 0.f, 0.f};
#pragma unroll
            for (int c4 = 0; c4 < 4; ++c4) {
                int r = st * 16 + fr;
                int cb = c4 * 64 + fg * 16;
                u16x8 ak = *(const u16x8*)(ksb + r * 256 + (cb ^ ((r & 7) << 4)));
                sacc = __builtin_amdgcn_mfma_f32_16x16x32_bf16(
                    as_bf(ak), as_bf(bq[c4]), sacc, 0, 0, 0);
            }
#pragma unroll
            for (int rr = 0; rr < 4; ++rr) {
                float sv = sacc[rr] * ATT_SCALE;
                if (diag) {
                    int kvg = kv0 + st * 16 + fg * 4 + rr;
                    sv = (kvg <= qrow_g) ? sv : -1e30f;
                }
                p[st][rr] = sv;
                mx = fmaxf(mx, sv);
            }
        }
        mx = fmaxf(mx, __shfl_xor(mx, 16));
        mx = fmaxf(mx, __shfl_xor(mx, 32));

        if (__all(mx - m_run <= 8.f)) {
            float rs = 0.f;
#pragma unroll
            for (int st = 0; st < 4; ++st) {
                u16x4 pw;
#pragma unroll
                for (int rr = 0; rr < 4; ++rr) {
                    float e = __expf(p[st][rr] - m_run);
                    rs += e;
                    pw[rr] = f2bf(e);
                }
                *(u16x4*)(psb + fr * 128 + ((st * 32 + fg * 8) ^ ((fr & 7) << 4))) = pw;
            }
            rs += __shfl_xor(rs, 16);
            rs += __shfl_xor(rs, 32);
            l_run += rs;
        } else {
            float m_new = fmaxf(m_run, mx);
            float corr = __expf(m_run - m_new);
            float rs = 0.f;
#pragma unroll
            for (int st = 0; st < 4; ++st) {
                u16x4 pw;
#pragma unroll
                for (int rr = 0; rr < 4; ++rr) {
                    float e = __expf(p[st][rr] - m_new);
                    rs += e;
                    pw[rr] = f2bf(e);
                }
                *(u16x4*)(psb + fr * 128 + ((st * 32 + fg * 8) ^ ((fr & 7) << 4))) = pw;
            }
            rs += __shfl_xor(rs, 16);
            rs += __shfl_xor(rs, 32);
            l_run = l_run * corr + rs;
            m_run = m_new;
            float ct[4];
#pragma unroll
            for (int rr = 0; rr < 4; ++rr) ct[rr] = __shfl(corr, fg * 4 + rr);
#pragma unroll
            for (int f = 0; f < 8; ++f)
#pragma unroll
                for (int rr = 0; rr < 4; ++rr) o[f][rr] *= ct[rr];
        }

#pragma unroll
        for (int ks = 0; ks < 2; ++ks) {
            u16x8 pa = *(const u16x8*)(psb + fr * 128 + ((ks * 64 + fg * 16) ^ ((fr & 7) << 4)));
#pragma unroll
            for (int f = 0; f < 8; ++f) {
                int d = f * 16 + fr;
                u16x8 vB = *(const u16x8*)(vsb + d * 128 + ((ks * 64 + fg * 16) ^ ((d & 7) << 4)));
                o[f] = __builtin_amdgcn_mfma_f32_16x16x32_bf16(
                    as_bf(pa), as_bf(vB), o[f], 0, 0, 0);
            }
        }
        __builtin_amdgcn_s_barrier();
    }

    float li[4];
#pragma unroll
    for (int rr = 0; rr < 4; ++rr) li[rr] = __shfl(l_run, fg * 4 + rr);
#pragma unroll
    for (int f = 0; f < 8; ++f)
#pragma unroll
        for (int rr = 0; rr < 4; ++rr) {
            int trow = q0 + fg * 4 + rr;
            float val = o[f][rr] / li[rr];
            xout[(size_t)trow * DMODEL + head * 128 + f * 16 + fr] = f2bf(val);
        }
}

extern "C" void kernel_launch(void* const* d_in, const int* in_sizes, int n_in,
                              void* d_out, int out_size, void* d_ws, size_t ws_size,
                              hipStream_t stream) {
    const float* x_in = (const float*)d_in[0];
    const float* w_qkv = (const float*)d_in[1];
    const float* w_o = (const float*)d_in[2];
    const float* cosb = (const float*)d_in[3];
    const float* sinb = (const float*)d_in[4];

    float* out = (float*)d_out;
    float* k_out = out + 4194304;
    float* v_out = out + 8388608;

    char* ws = (char*)d_ws;
    u16* xn    = (u16*)(ws);                         // 8 MiB  [T][D] bf16
    u16* w_bf  = (u16*)(ws + (size_t)(8u << 20));    // 24 MiB [3D][D] bf16
    u16* o_bf  = (u16*)(ws + (size_t)(32u << 20));   // 8 MiB  [D][D] bf16
    u16* qkv   = (u16*)(ws + (size_t)(40u << 20));   // 24 MiB [T][3D] bf16
    u16* q_bf  = (u16*)(ws + (size_t)(64u << 20));   // 8 MiB  [h][T][hd]
    u16* k_bf  = (u16*)(ws + (size_t)(72u << 20));   // 8 MiB
    u16* vt_bf = (u16*)(ws + (size_t)(80u << 20));   // 8 MiB  [h][hd][T]
    u16* x_bf  = (u16*)(ws + (size_t)(88u << 20));   // 8 MiB  [T][D]

    (void)hipFuncSetAttribute(reinterpret_cast<const void*>(&gemm256),
                              hipFuncAttributeMaxDynamicSharedMemorySize, 131072);

    cast_both<<<8192, 256, 0, stream>>>(w_qkv, w_o, w_bf, o_bf);
    rmsnorm_row<<<2048, 256, 0, stream>>>(x_in, xn);
    gemm256<<<dim3(24, 8), 512, 131072, stream>>>(xn, w_bf, qkv, 2048, 6144, 2048);
    rope_split<<<2048, 256, 0, stream>>>(qkv, cosb, sinb, q_bf, k_bf, k_out, v_out);
    vtrans<<<2048, 256, 0, stream>>>(qkv, vt_bf);
    attn_fwd<<<512, 256, 0, stream>>>(q_bf, k_bf, vt_bf, x_bf);
    gemm_bt<<<dim3(16, 16), 256, 0, stream>>>(x_bf, o_bf, out, x_in, 2048, 2048, 2048);
}

// Round 6
// 219.553 us; speedup vs baseline: 1.7004x; 1.0366x over previous
//
#include <hip/hip_runtime.h>
#include <hip/hip_bf16.h>

typedef unsigned short u16;
typedef unsigned int u32;
typedef __bf16 bf16x8 __attribute__((ext_vector_type(8)));
typedef u16 u16x8 __attribute__((ext_vector_type(8)));
typedef u16 u16x4 __attribute__((ext_vector_type(4)));
typedef float f32x4 __attribute__((ext_vector_type(4)));

#define T_SEQ 2048
#define DMODEL 2048
#define NHEAD 16
#define HDIM 128
#define ATT_SCALE 0.08838834764831843f

__device__ __forceinline__ u16 f2bf(float f) {
    return __builtin_bit_cast(u16, __float2bfloat16(f));
}
__device__ __forceinline__ bf16x8 as_bf(u16x8 v) {
    return __builtin_bit_cast(bf16x8, v);
}
__device__ __forceinline__ float lo2f(u32 w) { return __builtin_bit_cast(float, w << 16); }
__device__ __forceinline__ float hi2f(u32 w) { return __builtin_bit_cast(float, w & 0xffff0000u); }
__device__ __forceinline__ void gload_lds16(const u16* g, u16* l) {
    __builtin_amdgcn_global_load_lds(
        (const __attribute__((address_space(1))) u32*)(g),
        (__attribute__((address_space(3))) u32*)(l), 16, 0, 0);
}

// ---------------- fused weight casts fp32 -> bf16 ----------------
__global__ __launch_bounds__(256) void cast_both(const float* __restrict__ w1,
                                                 const float* __restrict__ w2,
                                                 u16* __restrict__ d1,
                                                 u16* __restrict__ d2) {
    int i = blockIdx.x * 256 + threadIdx.x;
    const float* src; u16* dst; int k;
    if (i < 1572864) { src = w1; dst = d1; k = i; }
    else             { src = w2; dst = d2; k = i - 1572864; }
    float4 a = ((const float4*)src)[2 * k];
    float4 b = ((const float4*)src)[2 * k + 1];
    u16x8 o;
    o[0] = f2bf(a.x); o[1] = f2bf(a.y); o[2] = f2bf(a.z); o[3] = f2bf(a.w);
    o[4] = f2bf(b.x); o[5] = f2bf(b.y); o[6] = f2bf(b.z); o[7] = f2bf(b.w);
    *(u16x8*)(dst + (size_t)k * 8) = o;
}

// ---------------- row RMSNorm over D=2048, write bf16 ----------------
__global__ __launch_bounds__(256) void rmsnorm_row(const float* __restrict__ x,
                                                   u16* __restrict__ xn) {
    const int row = blockIdx.x, tid = threadIdx.x;
    const float* xr = x + (size_t)row * DMODEL;
    float4 a = ((const float4*)xr)[2 * tid];
    float4 b = ((const float4*)xr)[2 * tid + 1];
    float ss = a.x*a.x + a.y*a.y + a.z*a.z + a.w*a.w
             + b.x*b.x + b.y*b.y + b.z*b.z + b.w*b.w;
#pragma unroll
    for (int off = 32; off; off >>= 1) ss += __shfl_xor(ss, off);
    __shared__ float red[4];
    if ((tid & 63) == 0) red[tid >> 6] = ss;
    __syncthreads();
    float tot = red[0] + red[1] + red[2] + red[3];
    float r = rsqrtf(tot * (1.f / DMODEL) + 1e-6f);
    u16x8 o;
    o[0] = f2bf(a.x*r); o[1] = f2bf(a.y*r); o[2] = f2bf(a.z*r); o[3] = f2bf(a.w*r);
    o[4] = f2bf(b.x*r); o[5] = f2bf(b.y*r); o[6] = f2bf(b.z*r); o[7] = f2bf(b.w*r);
    *(u16x8*)(xn + (size_t)row * DMODEL + tid * 8) = o;
}

// ---------------- 128x128 m97-style GEMM (out-proj, fp32 C + resid) --------
__global__ __launch_bounds__(256) void gemm_bt(const u16* __restrict__ A,
                                               const u16* __restrict__ B,
                                               float* __restrict__ C,
                                               const float* __restrict__ resid,
                                               int M, int N, int K) {
    __shared__ u16 As[128 * 32];
    __shared__ u16 Bs[128 * 32];
    const int bm = blockIdx.y * 128, bn = blockIdx.x * 128;
    const int tid = threadIdx.x, lane = tid & 63, wid = tid >> 6;
    const int wr = (wid >> 1) * 64, wc = (wid & 1) * 64;
    const int fr = lane & 15, fc = (lane >> 4) * 8;

    f32x4 acc[4][4] = {};
    const int r0 = tid >> 2, c0 = (tid & 3) << 3;
    const u16* a0p = A + (size_t)(bm + r0) * K + c0;
    const u16* a1p = A + (size_t)(bm + r0 + 64) * K + c0;
    const u16* b0p = B + (size_t)(bn + r0) * K + c0;
    const u16* b1p = B + (size_t)(bn + r0 + 64) * K + c0;
    u16* la0 = As + (size_t)tid * 8;
    u16* la1 = As + (size_t)(tid + 256) * 8;
    u16* lb0 = Bs + (size_t)tid * 8;
    u16* lb1 = Bs + (size_t)(tid + 256) * 8;

    for (int k0 = 0; k0 < K; k0 += 32) {
        gload_lds16(a0p + k0, la0);
        gload_lds16(a1p + k0, la1);
        gload_lds16(b0p + k0, lb0);
        gload_lds16(b1p + k0, lb1);
        __syncthreads();

        u16x8 af[4], bfm[4];
#pragma unroll
        for (int m = 0; m < 4; ++m)
            af[m] = *(const u16x8*)&As[(wr + m * 16 + fr) * 32 + fc];
#pragma unroll
        for (int n = 0; n < 4; ++n)
            bfm[n] = *(const u16x8*)&Bs[(wc + n * 16 + fr) * 32 + fc];
#pragma unroll
        for (int m = 0; m < 4; ++m)
#pragma unroll
            for (int n = 0; n < 4; ++n)
                acc[m][n] = __builtin_amdgcn_mfma_f32_16x16x32_bf16(
                    as_bf(af[m]), as_bf(bfm[n]), acc[m][n], 0, 0, 0);
        __syncthreads();
    }

#pragma unroll
    for (int m = 0; m < 4; ++m)
#pragma unroll
        for (int n = 0; n < 4; ++n)
#pragma unroll
            for (int r = 0; r < 4; ++r) {
                int row = bm + wr + m * 16 + (lane >> 4) * 4 + r;
                int col = bn + wc + n * 16 + fr;
                float val = acc[m][n][r];
                if (resid) val += resid[(size_t)row * N + col];
                C[(size_t)row * N + col] = val;
            }
}

// ---------------- 256x256 8-phase GEMM, gray-code operand reuse ------------
// Quadrant order per buf: (0,0)->(0,1)->(1,1)->(1,0); each phase reloads ONLY
// the changed operand. Staging placement (race-fixed, r5 post-mortem): stage
// region R strictly AFTER R's last register-load phase.
//   last reads: buf0 {A0@P1,B1@P2,A1@P3,B0@P4}; buf1 {A0@P5,B1@P6,A1@P7,B0@P8}
//   stages:     P1 A1(b1,kn1) P2 B0(b1,kn1) P3 A0(b0,kn2) P4 B1(b0,kn2)+VM4
//               P5 A1(b0,kn2) P6 B0(b0,kn2) P7 A0(b1,kn3) P8 B1(b1,kn3)+VM4
// Ledger: P4-VM4 drains {prev-P7 A0, prev-P8 B1, P1 A1, P2 B0} = full buf1
// tile before P5; P8-VM4 drains the four buf0/kn2 halves before next-P1.
#define VM4 asm volatile("s_waitcnt vmcnt(4)" ::: "memory");
#define VM0 asm volatile("s_waitcnt vmcnt(0)" ::: "memory");

#define LDA(BUF, MH)                                                          \
  _Pragma("unroll") for (int mq = 0; mq < 4; ++mq) {                          \
    int ra = wr + (MH) * 64 + mq * 16 + fr;                                   \
    int sw = ra & 7;                                                          \
    _Pragma("unroll") for (int k2 = 0; k2 < 2; ++k2)                          \
      av[mq][k2] = *(const u16x8*)(sA[BUF] + ra * 64 +                        \
                                   ((((k2 << 2) | fg) ^ sw) << 3));           \
  }

#define LDB(BUF, NH)                                                          \
  _Pragma("unroll") for (int nq = 0; nq < 2; ++nq) {                          \
    int rb = wc + (NH) * 32 + nq * 16 + fr;                                   \
    int sw = rb & 7;                                                          \
    _Pragma("unroll") for (int k2 = 0; k2 < 2; ++k2)                          \
      bv[nq][k2] = *(const u16x8*)(sB[BUF] + rb * 64 +                        \
                                   ((((k2 << 2) | fg) ^ sw) << 3));           \
  }

#define MFMAQ(MH, NH)                                                         \
  __builtin_amdgcn_s_barrier();                                               \
  __builtin_amdgcn_s_setprio(1);                                              \
  _Pragma("unroll") for (int k2 = 0; k2 < 2; ++k2)                            \
    _Pragma("unroll") for (int mq = 0; mq < 4; ++mq)                          \
      _Pragma("unroll") for (int nq = 0; nq < 2; ++nq)                        \
        acc[(MH) * 4 + mq][(NH) * 2 + nq] =                                   \
            __builtin_amdgcn_mfma_f32_16x16x32_bf16(                          \
                as_bf(av[mq][k2]), as_bf(bv[nq][k2]),                         \
                acc[(MH) * 4 + mq][(NH) * 2 + nq], 0, 0, 0);                  \
  __builtin_amdgcn_s_setprio(0);

#define ENDP                                                                  \
  __builtin_amdgcn_s_barrier();                                               \
  __builtin_amdgcn_sched_barrier(0);

__global__ __launch_bounds__(512) void gemm256(const u16* __restrict__ A,
                                               const u16* __restrict__ B,
                                               u16* __restrict__ C,
                                               int M, int N, int K) {
    extern __shared__ char smem[];
    const int tid = threadIdx.x, lane = tid & 63, wid = tid >> 6;
    const int bm = blockIdx.y * 256, bn = blockIdx.x * 256;
    const int wr = (wid >> 2) * 128, wc = (wid & 3) * 64;
    const int fr = lane & 15, fg = lane >> 4;

    u16* sA[2] = {(u16*)smem, (u16*)(smem + 65536)};
    u16* sB[2] = {(u16*)(smem + 32768), (u16*)(smem + 98304)};

    const int cs = (((tid & 7) ^ ((tid >> 3) & 7)) << 3);
    const int s8 = (tid & 7) << 3;
    const int rr6 = tid >> 3;
    const int rb0 = ((tid >> 8) << 6) + ((tid >> 3) & 31);

    auto stA = [&](int buf, int k0, int mh) {
#pragma unroll
        for (int j = 0; j < 2; ++j) {
            int r = j * 128 + mh * 64 + rr6;
            gload_lds16(A + (size_t)(bm + r) * K + k0 + cs, sA[buf] + r * 64 + s8);
        }
    };
    auto stB = [&](int buf, int k0, int nh) {
#pragma unroll
        for (int j = 0; j < 2; ++j) {
            int r = j * 128 + nh * 32 + rb0;
            gload_lds16(B + (size_t)(bn + r) * K + k0 + cs, sB[buf] + r * 64 + s8);
        }
    };

    f32x4 acc[8][4] = {};
    u16x8 av[4][2], bv[2][2];
    const int nt = K >> 6;

    // prologue: buf0 full (8 loads); buf1/kn1 halves A0,B1 (first-iter P1/P2
    // stage the complementary A1,B0).
    stA(0, 0, 0); stA(0, 0, 1); stB(0, 0, 0); stB(0, 0, 1);
    stA(1, 64, 0); stB(1, 64, 1);
    VM4
    __builtin_amdgcn_s_barrier();
    __builtin_amdgcn_sched_barrier(0);

    for (int it = 0; it < (nt >> 1); ++it) {
        const int kc = it << 7;
        const int kn1 = kc + 64, kn2 = kc + 128, kn3 = kc + 192;
        const bool st2 = (kn2 < K), st3 = (kn3 < K);

        // P1 (buf0; 0,0) load A0+B0 ; stage buf1-A1(kn1) [last read prev-P7]
        LDA(0, 0) LDB(0, 0)
        stA(1, kn1, 1);
        MFMAQ(0, 0) ENDP
        // P2 (buf0; 0,1) load B1 ; stage buf1-B0(kn1) [last read prev-P8]
        LDB(0, 1)
        stB(1, kn1, 0);
        MFMAQ(0, 1) ENDP
        // P3 (buf0; 1,1) load A1 ; stage buf0-A0(kn2) [last read P1]
        LDA(0, 1)
        if (st2) stA(0, kn2, 0);
        MFMAQ(1, 1) ENDP
        // P4 (buf0; 1,0) load B0 ; stage buf0-B1(kn2) [last read P2]
        LDB(0, 0)
        if (st2) stB(0, kn2, 1);
        MFMAQ(1, 0)
        if (st2) { VM4 } else { VM0 }
        ENDP
        // P5 (buf1; 0,0) load A0+B0 ; stage buf0-A1(kn2) [last read P3]
        LDA(1, 0) LDB(1, 0)
        if (st2) stA(0, kn2, 1);
        MFMAQ(0, 0) ENDP
        // P6 (buf1; 0,1) load B1 ; stage buf0-B0(kn2) [last read P4]
        LDB(1, 1)
        if (st2) stB(0, kn2, 0);
        MFMAQ(0, 1) ENDP
        // P7 (buf1; 1,1) load A1 ; stage buf1-A0(kn3) [last read P5]
        LDA(1, 1)
        if (st3) stA(1, kn3, 0);
        MFMAQ(1, 1) ENDP
        // P8 (buf1; 1,0) load B0 ; stage buf1-B1(kn3) [last read P6]
        LDB(1, 0)
        if (st3) stB(1, kn3, 1);
        MFMAQ(1, 0)
        VM4
        ENDP
    }

#pragma unroll
    for (int am = 0; am < 8; ++am)
#pragma unroll
        for (int bq = 0; bq < 4; ++bq)
#pragma unroll
            for (int r = 0; r < 4; ++r) {
                int row = bm + wr + am * 16 + fg * 4 + r;
                int col = bn + wc + bq * 16 + fr;
                C[(size_t)row * N + col] = f2bf(acc[am][bq][r]);
            }
}

// ---------------- per-head RMSNorm + RoPE (vectorized, bf16 qkv) -----------
__global__ __launch_bounds__(256) void rope_split(const u16* __restrict__ qkv,
                                                  const float* __restrict__ cosb,
                                                  const float* __restrict__ sinb,
                                                  u16* __restrict__ q_bf,
                                                  u16* __restrict__ k_bf,
                                                  float* __restrict__ k_out,
                                                  float* __restrict__ v_out) {
    const int t = blockIdx.x, tid = threadIdx.x, wid = tid >> 6, lane = tid & 63;
    const u16* row = qkv + (size_t)t * (3 * DMODEL);
    const int dp = (lane & 31) << 1;
    float2 c2 = *(const float2*)(cosb + t * 64 + dp);
    float2 s2 = *(const float2*)(sinb + t * 64 + dp);
    const bool hi = lane >= 32;

    for (int task = wid; task < 32; task += 4) {
        u32 w = *(const u32*)(row + task * 128 + lane * 2);
        float xa = lo2f(w), xb = hi2f(w);
        float ss = xa * xa + xb * xb;
#pragma unroll
        for (int off = 32; off; off >>= 1) ss += __shfl_xor(ss, off);
        float rn = rsqrtf(ss * (1.f / 128.f) + 1e-6f);
        float pa = __shfl_xor(xa, 32), pb = __shfl_xor(xb, 32);
        float oa, ob;
        if (!hi) {
            oa = (xa * c2.x - pa * s2.x) * rn;
            ob = (xb * c2.y - pb * s2.y) * rn;
        } else {
            oa = (pa * s2.x + xa * c2.x) * rn;
            ob = (pb * s2.y + xb * c2.y) * rn;
        }
        u32 pk = (u32)f2bf(oa) | ((u32)f2bf(ob) << 16);
        if (task < 16) {
            *(u32*)(q_bf + ((size_t)task * T_SEQ + t) * 128 + lane * 2) = pk;
        } else {
            int hh = task - 16;
            *(u32*)(k_bf + ((size_t)hh * T_SEQ + t) * 128 + lane * 2) = pk;
            float2 kk; kk.x = oa; kk.y = ob;
            *(float2*)(k_out + (size_t)t * DMODEL + hh * 128 + lane * 2) = kk;
        }
    }
    {
        u16x8 vv = *(const u16x8*)(row + 2 * DMODEL + tid * 8);
        float4 f0, f1;
        f0.x = __builtin_bit_cast(float, (u32)vv[0] << 16);
        f0.y = __builtin_bit_cast(float, (u32)vv[1] << 16);
        f0.z = __builtin_bit_cast(float, (u32)vv[2] << 16);
        f0.w = __builtin_bit_cast(float, (u32)vv[3] << 16);
        f1.x = __builtin_bit_cast(float, (u32)vv[4] << 16);
        f1.y = __builtin_bit_cast(float, (u32)vv[5] << 16);
        f1.z = __builtin_bit_cast(float, (u32)vv[6] << 16);
        f1.w = __builtin_bit_cast(float, (u32)vv[7] << 16);
        *(float4*)(v_out + (size_t)t * DMODEL + tid * 8) = f0;
        *(float4*)(v_out + (size_t)t * DMODEL + tid * 8 + 4) = f1;
    }
}

// ---------------- V transpose: qkv bf16 -> vt bf16 [h][128][T] -------------
__global__ __launch_bounds__(256) void vtrans(const u16* __restrict__ qkv,
                                              u16* __restrict__ vt) {
    const int b = blockIdx.x, tid = threadIdx.x;
    const int head = b >> 7;
    const int i = (b & 127) * 256 + tid;
    const int d = i & 127, tc = i >> 7;
    u16x8 o;
#pragma unroll
    for (int j = 0; j < 8; ++j)
        o[j] = qkv[(size_t)(tc * 8 + j) * (3 * DMODEL) + 2 * DMODEL + head * 128 + d];
    *(u16x8*)&vt[((size_t)head * 128 + d) * T_SEQ + tc * 8] = o;
}

// ---------------- causal flash attention (pipelined staging) ---------------
__global__ __launch_bounds__(256) void attn_fwd(const u16* __restrict__ qb,
                                                const u16* __restrict__ kb,
                                                const u16* __restrict__ vtb,
                                                u16* __restrict__ xout) {
    __shared__ u16 Ks[2][64 * 128];
    __shared__ u16 Vs[2][128 * 64];
    __shared__ u16 Ps[4][16 * 64];

    const int bid = blockIdx.x;
    const int r8 = bid & 7, s = bid >> 3;
    const int head = r8 + ((s >> 5) << 3);
    const int j = s & 31;
    const int qt = (s < 32) ? (31 - j) : j;

    const int tid = threadIdx.x, wid = tid >> 6, lane = tid & 63;
    const int fr = lane & 15, fg = lane >> 4;
    const u16* kh = kb + (size_t)head * T_SEQ * 128;
    const u16* vth = vtb + (size_t)head * 128 * T_SEQ;
    const u16* qh = qb + (size_t)head * T_SEQ * 128;
    const int q0 = qt * 64 + wid * 16;
    const int qrow_g = q0 + fr;

    u16x8 bq[4];
    {
        const u16* qrow = qh + (size_t)(q0 + fr) * 128 + fg * 8;
#pragma unroll
        for (int cc = 0; cc < 4; ++cc) bq[cc] = *(const u16x8*)(qrow + cc * 32);
    }

    auto stage = [&](int kv0, int buf) {
#pragma unroll
        for (int i = 0; i < 4; ++i) {
            int idx = i * 256 + tid;
            int r = idx >> 4;
            int cbs = ((idx & 15) << 4) ^ ((r & 7) << 4);
            gload_lds16(kh + (size_t)(kv0 + r) * 128 + (cbs >> 1), &Ks[buf][idx * 8]);
        }
#pragma unroll
        for (int i = 0; i < 4; ++i) {
            int idx = i * 256 + tid;
            int d = idx >> 3;
            int cbs = ((idx & 7) << 4) ^ ((d & 7) << 4);
            gload_lds16(vth + (size_t)d * T_SEQ + kv0 + (cbs >> 1), &Vs[buf][idx * 8]);
        }
    };

    stage(0, 0);

    f32x4 o[8] = {};
    float m_run = -1e30f, l_run = 0.f;
    const int nt = qt + 1;

    for (int kt = 0; kt < nt; ++kt) {
        const int kv0 = kt * 64;
        const int buf = kt & 1;
        if (kt + 1 < nt) {
            stage(kv0 + 64, buf ^ 1);
            asm volatile("s_waitcnt vmcnt(8)" ::: "memory");
        } else {
            asm volatile("s_waitcnt vmcnt(0)" ::: "memory");
        }
        __builtin_amdgcn_s_barrier();
        __builtin_amdgcn_sched_barrier(0);

        const char* ksb = (const char*)&Ks[buf][0];
        const char* vsb = (const char*)&Vs[buf][0];
        char* psb = (char*)&Ps[wid][0];

        float p[4][4];
        float mx = -1e30f;
        const bool diag = (kv0 + 64 > q0);
#pragma unroll
        for (int st = 0; st < 4; ++st) {
            f32x4 sacc = {0.f, 0.f, 0.f, 0.f};
#pragma unroll
            for (int c4 = 0; c4 < 4; ++c4) {
                int r = st * 16 + fr;
                int cb = c4 * 64 + fg * 16;
                u16x8 ak = *(const u16x8*)(ksb + r * 256 + (cb ^ ((r & 7) << 4)));
                sacc = __builtin_amdgcn_mfma_f32_16x16x32_bf16(
                    as_bf(ak), as_bf(bq[c4]), sacc, 0, 0, 0);
            }
#pragma unroll
            for (int rr = 0; rr < 4; ++rr) {
                float sv = sacc[rr] * ATT_SCALE;
                if (diag) {
                    int kvg = kv0 + st * 16 + fg * 4 + rr;
                    sv = (kvg <= qrow_g) ? sv : -1e30f;
                }
                p[st][rr] = sv;
                mx = fmaxf(mx, sv);
            }
        }
        mx = fmaxf(mx, __shfl_xor(mx, 16));
        mx = fmaxf(mx, __shfl_xor(mx, 32));

        if (__all(mx - m_run <= 8.f)) {
            float rs = 0.f;
#pragma unroll
            for (int st = 0; st < 4; ++st) {
                u16x4 pw;
#pragma unroll
                for (int rr = 0; rr < 4; ++rr) {
                    float e = __expf(p[st][rr] - m_run);
                    rs += e;
                    pw[rr] = f2bf(e);
                }
                *(u16x4*)(psb + fr * 128 + ((st * 32 + fg * 8) ^ ((fr & 7) << 4))) = pw;
            }
            rs += __shfl_xor(rs, 16);
            rs += __shfl_xor(rs, 32);
            l_run += rs;
        } else {
            float m_new = fmaxf(m_run, mx);
            float corr = __expf(m_run - m_new);
            float rs = 0.f;
#pragma unroll
            for (int st = 0; st < 4; ++st) {
                u16x4 pw;
#pragma unroll
                for (int rr = 0; rr < 4; ++rr) {
                    float e = __expf(p[st][rr] - m_new);
                    rs += e;
                    pw[rr] = f2bf(e);
                }
                *(u16x4*)(psb + fr * 128 + ((st * 32 + fg * 8) ^ ((fr & 7) << 4))) = pw;
            }
            rs += __shfl_xor(rs, 16);
            rs += __shfl_xor(rs, 32);
            l_run = l_run * corr + rs;
            m_run = m_new;
            float ct[4];
#pragma unroll
            for (int rr = 0; rr < 4; ++rr) ct[rr] = __shfl(corr, fg * 4 + rr);
#pragma unroll
            for (int f = 0; f < 8; ++f)
#pragma unroll
                for (int rr = 0; rr < 4; ++rr) o[f][rr] *= ct[rr];
        }

#pragma unroll
        for (int ks = 0; ks < 2; ++ks) {
            u16x8 pa = *(const u16x8*)(psb + fr * 128 + ((ks * 64 + fg * 16) ^ ((fr & 7) << 4)));
#pragma unroll
            for (int f = 0; f < 8; ++f) {
                int d = f * 16 + fr;
                u16x8 vB = *(const u16x8*)(vsb + d * 128 + ((ks * 64 + fg * 16) ^ ((d & 7) << 4)));
                o[f] = __builtin_amdgcn_mfma_f32_16x16x32_bf16(
                    as_bf(pa), as_bf(vB), o[f], 0, 0, 0);
            }
        }
        __builtin_amdgcn_s_barrier();
    }

    float li[4];
#pragma unroll
    for (int rr = 0; rr < 4; ++rr) li[rr] = __shfl(l_run, fg * 4 + rr);
#pragma unroll
    for (int f = 0; f < 8; ++f)
#pragma unroll
        for (int rr = 0; rr < 4; ++rr) {
            int trow = q0 + fg * 4 + rr;
            float val = o[f][rr] / li[rr];
            xout[(size_t)trow * DMODEL + head * 128 + f * 16 + fr] = f2bf(val);
        }
}

extern "C" void kernel_launch(void* const* d_in, const int* in_sizes, int n_in,
                              void* d_out, int out_size, void* d_ws, size_t ws_size,
                              hipStream_t stream) {
    const float* x_in = (const float*)d_in[0];
    const float* w_qkv = (const float*)d_in[1];
    const float* w_o = (const float*)d_in[2];
    const float* cosb = (const float*)d_in[3];
    const float* sinb = (const float*)d_in[4];

    float* out = (float*)d_out;
    float* k_out = out + 4194304;
    float* v_out = out + 8388608;

    char* ws = (char*)d_ws;
    u16* xn    = (u16*)(ws);                         // 8 MiB  [T][D] bf16
    u16* w_bf  = (u16*)(ws + (size_t)(8u << 20));    // 24 MiB [3D][D] bf16
    u16* o_bf  = (u16*)(ws + (size_t)(32u << 20));   // 8 MiB  [D][D] bf16
    u16* qkv   = (u16*)(ws + (size_t)(40u << 20));   // 24 MiB [T][3D] bf16
    u16* q_bf  = (u16*)(ws + (size_t)(64u << 20));   // 8 MiB  [h][T][hd]
    u16* k_bf  = (u16*)(ws + (size_t)(72u << 20));   // 8 MiB
    u16* vt_bf = (u16*)(ws + (size_t)(80u << 20));   // 8 MiB  [h][hd][T]
    u16* x_bf  = (u16*)(ws + (size_t)(88u << 20));   // 8 MiB  [T][D]

    (void)hipFuncSetAttribute(reinterpret_cast<const void*>(&gemm256),
                              hipFuncAttributeMaxDynamicSharedMemorySize, 131072);

    cast_both<<<8192, 256, 0, stream>>>(w_qkv, w_o, w_bf, o_bf);
    rmsnorm_row<<<2048, 256, 0, stream>>>(x_in, xn);
    gemm256<<<dim3(24, 8), 512, 131072, stream>>>(xn, w_bf, qkv, 2048, 6144, 2048);
    rope_split<<<2048, 256, 0, stream>>>(qkv, cosb, sinb, q_bf, k_bf, k_out, v_out);
    vtrans<<<2048, 256, 0, stream>>>(qkv, vt_bf);
    attn_fwd<<<512, 256, 0, stream>>>(q_bf, k_bf, vt_bf, x_bf);
    gemm_bt<<<dim3(16, 16), 256, 0, stream>>>(x_bf, o_bf, out, x_in, 2048, 2048, 2048);
}